// Round 10
// baseline (557.978 us; speedup 1.0000x reference)
//
#include <hip/hip_runtime.h>
#include <math.h>

#define B_ 2
#define S_ 1024
#define HID 4096
#define NH 32
#define NKV 8
#define HD 128
#define LOG2E 1.44269504088896340736f

typedef short s16x8 __attribute__((ext_vector_type(8)));   // 8 bf16 (4 VGPRs)
typedef float f32x4 __attribute__((ext_vector_type(4)));
typedef unsigned short u16;
typedef u16 u16x4 __attribute__((ext_vector_type(4)));

__device__ __forceinline__ f32x4 mfma16(s16x8 a, s16x8 b, f32x4 c) {
  return __builtin_amdgcn_mfma_f32_16x16x32_bf16(a, b, c, 0, 0, 0);
}
// exact for integer-valued floats |v| <= 127
__device__ __forceinline__ u16 f2bf(float f) {
  union { float f; unsigned u; } v; v.f = f;
  return (u16)(v.u >> 16);
}
__device__ __forceinline__ float get_scale(const unsigned* sc, int slot) {
  return fmaxf(__uint_as_float(sc[slot]) / 127.0f, 1e-8f);
}
__device__ __forceinline__ void gload16(const void* g, void* l) {
  __builtin_amdgcn_global_load_lds(
      (const __attribute__((address_space(1))) unsigned*)g,
      (__attribute__((address_space(3))) unsigned*)l, 16, 0, 0);
}
__device__ __forceinline__ void atomic_absmax(unsigned* out, float m, int lane) {
  #pragma unroll
  for (int o = 32; o >= 1; o >>= 1) m = fmaxf(m, __shfl_xor(m, o));
  if (lane == 0) atomicMax(out, __float_as_uint(m));
}

#define SB_() __builtin_amdgcn_sched_barrier(0)
#define PBAR() do { SB_(); __builtin_amdgcn_s_barrier(); SB_(); } while (0)
#define VM6() do { SB_(); asm volatile("s_waitcnt vmcnt(6)" ::: "memory"); } while (0)
#define VM0() do { SB_(); asm volatile("s_waitcnt vmcnt(0)" ::: "memory"); } while (0)

// ---------------- fused absmax over the 5 input tensors ---------------------
__global__ void absmax5_k(const float4* __restrict__ p0, const float4* __restrict__ p1,
                          const float4* __restrict__ p2, const float4* __restrict__ p3,
                          const float4* __restrict__ p4, unsigned* __restrict__ sc) {
  int r = blockIdx.y;
  const float4* x; int n4;
  if (r == 0)      { x = p0; n4 = B_ * S_ * HID / 4; }
  else if (r == 1) { x = p1; n4 = HID * HID / 4; }
  else if (r == 2) { x = p2; n4 = NKV * HD * HID / 4; }
  else if (r == 3) { x = p3; n4 = NKV * HD * HID / 4; }
  else             { x = p4; n4 = HID * HID / 4; }
  float m = 0.f;
  int stride = gridDim.x * blockDim.x;
  for (int i = blockIdx.x * blockDim.x + threadIdx.x; i < n4; i += stride) {
    float4 v = x[i];
    m = fmaxf(m, fmaxf(fmaxf(fabsf(v.x), fabsf(v.y)), fmaxf(fabsf(v.z), fabsf(v.w))));
  }
  atomic_absmax(sc + r, m, threadIdx.x & 63);
}

// ---------------- fused quantize of the 5 input tensors ---------------------
__global__ void quant5_k(const float4* __restrict__ p0, const float4* __restrict__ p1,
                         const float4* __restrict__ p2, const float4* __restrict__ p3,
                         const float4* __restrict__ p4,
                         u16x4* __restrict__ y0, u16x4* __restrict__ y1,
                         u16x4* __restrict__ y2, u16x4* __restrict__ y3,
                         u16x4* __restrict__ y4, const unsigned* __restrict__ sc) {
  int r = blockIdx.y;
  const float4* x; u16x4* y; int n4;
  if (r == 0)      { x = p0; y = y0; n4 = B_ * S_ * HID / 4; }
  else if (r == 1) { x = p1; y = y1; n4 = HID * HID / 4; }
  else if (r == 2) { x = p2; y = y2; n4 = NKV * HD * HID / 4; }
  else if (r == 3) { x = p3; y = y3; n4 = NKV * HD * HID / 4; }
  else             { x = p4; y = y4; n4 = HID * HID / 4; }
  float s = get_scale(sc, r);
  int stride = gridDim.x * blockDim.x;
  for (int i = blockIdx.x * blockDim.x + threadIdx.x; i < n4; i += stride) {
    float4 v = x[i];
    u16x4 o;
    o[0] = f2bf(fminf(fmaxf(rintf(v.x / s), -127.f), 127.f));
    o[1] = f2bf(fminf(fmaxf(rintf(v.y / s), -127.f), 127.f));
    o[2] = f2bf(fminf(fmaxf(rintf(v.z / s), -127.f), 127.f));
    o[3] = f2bf(fminf(fmaxf(rintf(v.w / s), -127.f), 127.f));
    y[i] = o;
  }
}

// ---------------- generic quantize (attn output) ----------------------------
__global__ void quant_k(const float4* __restrict__ x, u16x4* __restrict__ y, int n4,
                        const unsigned* __restrict__ sc, int slot) {
  float s = get_scale(sc, slot);
  int stride = gridDim.x * blockDim.x;
  for (int i = blockIdx.x * blockDim.x + threadIdx.x; i < n4; i += stride) {
    float4 v = x[i];
    u16x4 o;
    o[0] = f2bf(fminf(fmaxf(rintf(v.x / s), -127.f), 127.f));
    o[1] = f2bf(fminf(fmaxf(rintf(v.y / s), -127.f), 127.f));
    o[2] = f2bf(fminf(fmaxf(rintf(v.z / s), -127.f), 127.f));
    o[3] = f2bf(fminf(fmaxf(rintf(v.w / s), -127.f), 127.f));
    y[i] = o;
  }
}

// ---------------- split-K reduce: out = P0 + P1 (scale pre-applied) ---------
__global__ void add_k(const float4* __restrict__ p0, const float4* __restrict__ p1,
                      float4* __restrict__ out, int n4) {
  int stride = gridDim.x * blockDim.x;
  for (int i = blockIdx.x * blockDim.x + threadIdx.x; i < n4; i += stride) {
    float4 a = p0[i], b = p1[i];
    out[i] = make_float4(a.x + b.x, a.y + b.y, a.z + b.z, a.w + b.w);
  }
}

// ================= 256x256 8-phase GEMM (T2+T3+T4+T5) ========================
// C[M,N] = (A[M,k0:k0+nkt*64] * B^T) * scale.  BK=64, 8 waves (2M x 4N).
// LDS 128KB.  Steady state at ph4's vmcnt(6): 14 outstanding -> retires 8
// oldest = all of buf1 tile t+1.  TAIL (t=nkt-2): ph2-4 stages guarded off ->
// only 8 outstanding, so drain vmcnt(0) to cover tile nkt-1.  nkt even, >=2.
__device__ __forceinline__ void rdA(const u16* slot, int wm, int lr, int lg,
                                    s16x8 af[4][2]) {
  #pragma unroll
  for (int mi = 0; mi < 4; ++mi) {
    int row = wm * 64 + mi * 16 + lr;
    const char* base = (const char*)slot + row * 128;
    int sw = (row & 7) << 4;
    #pragma unroll
    for (int ks = 0; ks < 2; ++ks)
      af[mi][ks] = *(const s16x8*)(base + ((ks * 64 + lg * 16) ^ sw));
  }
}
__device__ __forceinline__ void rdB(const u16* slot, int wn, int lr, int lg,
                                    s16x8 bf[2][2]) {
  #pragma unroll
  for (int ni = 0; ni < 2; ++ni) {
    int row = wn * 32 + ni * 16 + lr;
    const char* base = (const char*)slot + row * 128;
    int sw = (row & 7) << 4;
    #pragma unroll
    for (int ks = 0; ks < 2; ++ks)
      bf[ni][ks] = *(const s16x8*)(base + ((ks * 64 + lg * 16) ^ sw));
  }
}
template <int PM, int PN>
__device__ __forceinline__ void mfma_phase(f32x4 (&acc)[2][2][4][2],
                                           const s16x8 (&af)[4][2],
                                           const s16x8 (&bf)[2][2]) {
  __builtin_amdgcn_s_setprio(1);
  #pragma unroll
  for (int mi = 0; mi < 4; ++mi)
    #pragma unroll
    for (int ni = 0; ni < 2; ++ni)
      #pragma unroll
      for (int ks = 0; ks < 2; ++ks)
        acc[PM][PN][mi][ni] = mfma16(af[mi][ks], bf[ni][ks], acc[PM][PN][mi][ni]);
  __builtin_amdgcn_s_setprio(0);
}

__device__ void gemm256(const u16* __restrict__ A, const u16* __restrict__ Bm,
                        float* __restrict__ C, int Ncols, int m0, int n0,
                        int k0, int nkt, float scale, unsigned* omax, u16* S) {
  const int tid = threadIdx.x;
  const int wave = tid >> 6, lane = tid & 63;
  const int lr = lane & 15, lg = lane >> 4;
  const int wm = wave >> 2, wn = wave & 3;
  u16* SA00 = S;          u16* SA01 = S + 8192;
  u16* SB00 = S + 16384;  u16* SB01 = S + 24576;
  u16* SA10 = S + 32768;  u16* SA11 = S + 40960;
  u16* SB10 = S + 49152;  u16* SB11 = S + 57344;
  // staging: thread t covers rows r0, r0+64 at pre-swizzled col ce
  const int r0 = tid >> 3;
  const int ce = (((tid & 7) * 16) ^ ((r0 & 7) << 4)) >> 1;
  const u16* pa0 = A + (size_t)(m0 + r0) * HID + k0 + ce;
  const u16* pa1 = pa0 + (size_t)128 * HID;
  const u16* pb0 = Bm + (size_t)(n0 + r0) * HID + k0 + ce;
  const u16* pb1 = pb0 + (size_t)128 * HID;
  const int wdst = wave * 512;
  f32x4 acc[2][2][4][2] = {};
  s16x8 af[4][2], bf[2][2];

  auto STG = [&](const u16* p, u16* slot, int tcol) {
    const u16* g = p + tcol * 64;
    gload16(g, slot + wdst);
    gload16(g + (size_t)64 * HID, slot + 4096 + wdst);
  };

  // prologue: tile0 complete + 3 half-tiles of tile1 in flight
  STG(pa0, SA00, 0); STG(pb0, SB00, 0); STG(pa1, SA01, 0); STG(pb1, SB01, 0);
  STG(pa0, SA10, 1); STG(pb1, SB11, 1); STG(pa1, SA11, 1);
  VM6(); PBAR();

  #pragma unroll 1
  for (int t = 0; t < nkt; t += 2) {
    const bool g2 = t + 2 < nkt, g3 = t + 3 < nkt;
    // ph1 (0,0) on tile t (buf0)
    rdA(SA00, wm, lr, lg, af); rdB(SB00, wn, lr, lg, bf);
    STG(pb0, SB10, t + 1);
    PBAR(); mfma_phase<0, 0>(acc, af, bf); PBAR();
    // ph2 (0,1)
    rdB(SB01, wn, lr, lg, bf);
    if (g2) STG(pa0, SA00, t + 2);
    PBAR(); mfma_phase<0, 1>(acc, af, bf); PBAR();
    // ph3 (1,1)
    rdA(SA01, wm, lr, lg, af);
    if (g2) STG(pb1, SB01, t + 2);
    PBAR(); mfma_phase<1, 1>(acc, af, bf); PBAR();
    // ph4 (1,0)
    rdB(SB00, wn, lr, lg, bf);
    if (g2) STG(pa1, SA01, t + 2);
    PBAR(); mfma_phase<1, 0>(acc, af, bf);
    if (g2) { VM6(); } else { VM0(); }  // tail: drain last-tile stages fully
    PBAR();
    // ph5 (0,0) on tile t+1 (buf1)
    rdA(SA10, wm, lr, lg, af); rdB(SB10, wn, lr, lg, bf);
    if (g2) STG(pb0, SB00, t + 2);
    PBAR(); mfma_phase<0, 0>(acc, af, bf); PBAR();
    // ph6 (0,1)
    rdB(SB11, wn, lr, lg, bf);
    if (g3) STG(pa0, SA10, t + 3);
    PBAR(); mfma_phase<0, 1>(acc, af, bf); PBAR();
    // ph7 (1,1)
    rdA(SA11, wm, lr, lg, af);
    if (g3) STG(pb1, SB11, t + 3);
    PBAR(); mfma_phase<1, 1>(acc, af, bf); PBAR();
    // ph8 (1,0)
    rdB(SB10, wn, lr, lg, bf);
    if (g3) STG(pa1, SA11, t + 3);
    PBAR(); mfma_phase<1, 0>(acc, af, bf); VM6(); PBAR();
  }

  float gm = 0.f;
  #pragma unroll
  for (int mh = 0; mh < 2; ++mh)
    #pragma unroll
    for (int nh = 0; nh < 2; ++nh)
      #pragma unroll
      for (int mi = 0; mi < 4; ++mi)
        #pragma unroll
        for (int ni = 0; ni < 2; ++ni) {
          size_t rbase = (size_t)(m0 + mh * 128 + wm * 64 + mi * 16 + lg * 4);
          int cb = n0 + nh * 128 + wn * 32 + ni * 16 + lr;
          #pragma unroll
          for (int r = 0; r < 4; ++r) {
            float v = acc[mh][nh][mi][ni][r] * scale;
            gm = fmaxf(gm, fabsf(v));
            C[(rbase + r) * (size_t)Ncols + cb] = v;
          }
        }
  if (omax) atomic_absmax(omax, gm, lane);
}

// fused Q/K/V projection: 192 blocks (8 M-tiles x 24 N-tiles), XCD-swizzled
__global__ __launch_bounds__(512, 1) void gemm_qkv8(
    const u16* __restrict__ Xq, const u16* __restrict__ Wqb,
    const u16* __restrict__ Wkb, const u16* __restrict__ Wvb,
    float* __restrict__ qf, float* __restrict__ kf, float* __restrict__ vf,
    const unsigned* __restrict__ sc, unsigned* __restrict__ vmax) {
  extern __shared__ __align__(16) u16 S[];
  int raw = blockIdx.x;
  int wg = (raw & 7) * 24 + (raw >> 3);
  int bx = wg & 7, by = wg >> 3;
  const u16* Bm; float* C; int Ncols, n0, sslot; unsigned* om = nullptr;
  if (by < 16)      { Bm = Wqb; C = qf; Ncols = HID;      n0 = by * 256;        sslot = 1; }
  else if (by < 20) { Bm = Wkb; C = kf; Ncols = NKV * HD; n0 = (by - 16) * 256; sslot = 2; }
  else              { Bm = Wvb; C = vf; Ncols = NKV * HD; n0 = (by - 20) * 256; sslot = 3; om = vmax; }
  float scale = get_scale(sc, 0) * get_scale(sc, sslot);
  gemm256(Xq, Bm, C, Ncols, bx * 256, n0, 0, 64, scale, om, S);
}

// O projection, split-K=2: 256 blocks (128 tiles x 2 K-halves), XCD-swizzled
__global__ __launch_bounds__(512, 1) void gemm_o8(
    const u16* __restrict__ A, const u16* __restrict__ Bm,
    float* __restrict__ P0, float* __restrict__ P1,
    const unsigned* __restrict__ sc) {
  extern __shared__ __align__(16) u16 S[];
  int raw = blockIdx.x;
  int wg = (raw & 7) * 32 + (raw >> 3);   // 256 = 8 XCD x 32, bijective
  int tile = wg >> 1, half = wg & 1;
  int by = tile & 15, bx = tile >> 4;
  float scale = get_scale(sc, 8) * get_scale(sc, 4);
  gemm256(A, Bm, half ? P1 : P0, HID, bx * 256, by * 256, half * 2048, 32,
          scale, nullptr, S);
}

// ---------------- RoPE cos/sin table (pos x 64) -----------------------------
__global__ void rope_tab_k(float2* __restrict__ tab) {
  int i = blockIdx.x * 256 + threadIdx.x;  // 65536
  int pos = i >> 6, d = i & 63;
  float inv = exp2f((float)d * (-13.287712379549449f / 64.0f));
  float ang = (float)pos * inv;
  tab[i] = make_float2(cosf(ang), sinf(ang));
}

// ---------------- RoPE in-place + absmax, q & k fused -----------------------
__global__ void rope2_k(float* __restrict__ qf, float* __restrict__ kf,
                        unsigned* __restrict__ sc, const float2* __restrict__ tab) {
  int reg = blockIdx.y;
  float* q = reg ? kf : qf;
  int nheads = reg ? NKV : NH;
  unsigned* om = sc + (reg ? 6 : 5);
  int total = B_ * S_ * nheads * 64;
  int stride = gridDim.x * blockDim.x;
  float m = 0.f;
  for (int i = blockIdx.x * blockDim.x + threadIdx.x; i < total; i += stride) {
    int d = i & 63;
    int h = (i >> 6) % nheads;
    int bs = i / (64 * nheads);
    int pos = bs & (S_ - 1);
    float2 cs = tab[(pos << 6) + d];
    size_t base = ((size_t)bs * nheads + h) * HD + d;
    float x1 = q[base], x2 = q[base + 64];
    float o1 = x1 * cs.x - x2 * cs.y;
    float o2 = x2 * cs.x + x1 * cs.y;
    q[base] = o1; q[base + 64] = o2;
    m = fmaxf(m, fmaxf(fabsf(o1), fabsf(o2)));
  }
  atomic_absmax(om, m, threadIdx.x & 63);
}

// ---------------- quantize q & k fused --------------------------------------
__global__ void quantqk_k(const float4* __restrict__ qf, const float4* __restrict__ kf,
                          u16x4* __restrict__ qq, u16x4* __restrict__ kq,
                          const unsigned* __restrict__ sc) {
  int reg = blockIdx.y;
  const float4* x = reg ? kf : qf;
  u16x4* y = reg ? kq : qq;
  int n4 = reg ? (B_ * S_ * NKV * HD / 4) : (B_ * S_ * HID / 4);
  float s = get_scale(sc, reg ? 6 : 5);
  int stride = gridDim.x * blockDim.x;
  for (int i = blockIdx.x * blockDim.x + threadIdx.x; i < n4; i += stride) {
    float4 v = x[i];
    u16x4 o;
    o[0] = f2bf(fminf(fmaxf(rintf(v.x / s), -127.f), 127.f));
    o[1] = f2bf(fminf(fmaxf(rintf(v.y / s), -127.f), 127.f));
    o[2] = f2bf(fminf(fmaxf(rintf(v.z / s), -127.f), 127.f));
    o[3] = f2bf(fminf(fmaxf(rintf(v.w / s), -127.f), 127.f));
    y[i] = o;
  }
}

// ---------------- V: quantize + transpose to (B,NKV,HD,S), LDS-tiled --------
__global__ __launch_bounds__(256) void vquant_t_k(const float* __restrict__ vf,
                                                  unsigned* __restrict__ vtw,
                                                  const unsigned* __restrict__ sc) {
  __shared__ u16 Ls[64 * 132];
  float s = get_scale(sc, 7);
  int st = blockIdx.x & 15, kvh = (blockIdx.x >> 4) & 7, b = blockIdx.x >> 7;
  int s0 = st * 64;
  #pragma unroll
  for (int i = 0; i < 8; ++i) {
    int o = i * 256 + threadIdx.x;
    int sr = o >> 5, c4 = o & 31;
    float4 v = *(const float4*)(vf + ((size_t)(b * S_ + s0 + sr)) * (NKV * HD) +
                                kvh * HD + c4 * 4);
    u16x4 w;
    w[0] = f2bf(fminf(fmaxf(rintf(v.x / s), -127.f), 127.f));
    w[1] = f2bf(fminf(fmaxf(rintf(v.y / s), -127.f), 127.f));
    w[2] = f2bf(fminf(fmaxf(rintf(v.z / s), -127.f), 127.f));
    w[3] = f2bf(fminf(fmaxf(rintf(v.w / s), -127.f), 127.f));
    *(u16x4*)(Ls + sr * 132 + c4 * 4) = w;
  }
  __syncthreads();
  #pragma unroll
  for (int i = 0; i < 16; ++i) {
    int o = i * 256 + threadIdx.x;
    int d = o >> 5, sj = o & 31;
    unsigned lo = Ls[(sj * 2) * 132 + d], hi = Ls[(sj * 2 + 1) * 132 + d];
    vtw[(((size_t)(b * NKV + kvh) * HD + d) << 9) + st * 32 + sj] = lo | (hi << 16);
  }
}

// ---------------- two-pass quantized causal GQA attention -------------------
// QBLK=128, 8 waves (512 thr): each wave owns 16 q-rows (geometry identical
// to the proven 4-wave version), but K/V staging is shared by all 8 waves ->
// staging traffic and barriers per unit work HALVE.  Grid 256 = exactly one
// chip wave; block pairing {qp, 7-qp} gives uniform 18 K-stages/block.
// XCD-grouped decode: the 16 blocks sharing (b,kvh) land on one XCD so their
// 512KB K+V working set stays L2-resident.  Fixed softmax reference M0 (no
// online max); causal mask applied per-wave-uniformly only on non-interior
// tiles.  Depth-1 async dbuf staging; Ps wave-private (no mid barrier).
__global__ __launch_bounds__(512) void attn_k(
    const u16* __restrict__ Q, const u16* __restrict__ Kq, const u16* __restrict__ Vt,
    float* __restrict__ O, const unsigned* __restrict__ sc, unsigned* __restrict__ omax) {
  __shared__ __align__(16) u16 Ks[2][64 * 128];    // 2 x 16KB
  __shared__ __align__(16) u16 Vs[2][128 * 64];    // 2 x 16KB
  __shared__ __align__(16) u16 Ps[128 * 64];       // 16KB, wave-private rows
  const int tid = threadIdx.x;
  const int wave = tid >> 6, lane = tid & 63;
  const int lr = lane & 15, lg = lane >> 4;
  // XCD-grouped decode: 256 blocks = 8 xcd x 32; per xcd two (b,kvh) groups.
  const int raw = blockIdx.x;
  const int xcd = raw & 7, j = raw >> 3;
  const int grp = xcd + 8 * (j >> 4);    // 0..15 = (b, kvh)
  const int within = j & 15;             // 4 h-in-group x 4 q-pairs
  const int b = grp >> 3, kvh = grp & 7;
  const int h = kvh * 4 + (within >> 2);
  const int qp = within & 3;
  const float sq = get_scale(sc, 5), sk = get_scale(sc, 6), sv = get_scale(sc, 7);
  const float c2 = sq * sk * 0.08838834764831845f * LOG2E;
  const float M0 = 32.0f;
  const int k_rin = lane >> 4;
  const int k_cb0 = (lane & 15) * 16;
  const int v_rin = lane >> 3;
  const int v_cb = ((lane & 7) * 16) ^ ((v_rin & 7) << 4);
  float gmax = 0.f;

  auto stageK = [&](int buf, int kt) {
    #pragma unroll
    for (int i = 0; i < 2; ++i) {
      int ch = wave * 2 + i;
      int row = ch * 4 + k_rin;
      int cb = k_cb0 ^ ((row & 7) << 4);
      gload16(Kq + (size_t)(b * S_ + kt * 64 + row) * (NKV * HD) + kvh * HD + (cb >> 1),
              Ks[buf] + ch * 512);
    }
  };
  auto stageV = [&](int buf, int kt) {
    #pragma unroll
    for (int i = 0; i < 2; ++i) {
      int ch = wave * 2 + i;
      int vrow = ch * 8 + v_rin;
      gload16(Vt + ((size_t)(b * NKV + kvh) * HD + vrow) * S_ + kt * 64 + (v_cb >> 1),
              Vs[buf] + ch * 512);
    }
  };

  for (int pi = 0; pi < 2; ++pi) {
    const int qt = pi ? 7 - qp : qp;      // 128-row q-block index
    const int q0 = qt * 128;
    const int nkt = 2 * (qt + 1);
    const int qwmin = q0 + wave * 16;     // wave's lowest q-row
    s16x8 aq[4];
    {
      const u16* qp_ = Q + (size_t)(b * S_ + q0 + wave * 16 + lr) * HID + h * HD + lg * 8;
      #pragma unroll
      for (int ks = 0; ks < 4; ++ks) aq[ks] = *(const s16x8*)(qp_ + ks * 32);
    }
    float ll[4] = {0.f, 0.f, 0.f, 0.f};

    // ---- pass 1: denominator only, fixed reference M0 ----
    stageK(0, 0);
    __syncthreads();
    for (int kt = 0; kt < nkt; ++kt) {
      const int p = kt & 1;
      if (kt < nkt - 1) stageK(p ^ 1, kt + 1);
      f32x4 sacc[4] = {};
      __builtin_amdgcn_s_setprio(1);
      #pragma unroll
      for (int ks = 0; ks < 4; ++ks)
        #pragma unroll
        for (int n = 0; n < 4; ++n) {
          int row = n * 16 + lr;
          s16x8 bk = *(const s16x8*)((const char*)Ks[p] + row * 256 +
                                     ((ks * 64 + lg * 16) ^ ((row & 7) << 4)));
          sacc[n] = mfma16(aq[ks], bk, sacc[n]);
        }
      __builtin_amdgcn_s_setprio(0);
      if (kt * 64 + 63 <= qwmin) {        // interior for this wave
        #pragma unroll
        for (int r = 0; r < 4; ++r)
          #pragma unroll
          for (int n = 0; n < 4; ++n)
            ll[r] += exp2f(fmaf(sacc[n][r], c2, -M0));
      } else {
        #pragma unroll
        for (int r = 0; r < 4; ++r) {
          int qg = qwmin + lg * 4 + r;
          #pragma unroll
          for (int n = 0; n < 4; ++n) {
            int kg = kt * 64 + n * 16 + lr;
            float e = exp2f(fmaf(sacc[n][r], c2, -M0));
            ll[r] += (kg <= qg) ? e : 0.f;
          }
        }
      }
      __syncthreads();  // drains this iter's stage loads; guards buffer reuse
    }
    float bias[4];
    #pragma unroll
    for (int r = 0; r < 4; ++r) {
      float l = ll[r];
      #pragma unroll
      for (int o = 8; o >= 1; o >>= 1) l += __shfl_xor(l, o);
      bias[r] = 6.9886846867721655f - __log2f(l) - M0;  // log2(127) - log2(l) - M0
    }

    // ---- pass 2: recompute S, quantize P, PV ----
    f32x4 oacc[8] = {};
    stageK(0, 0); stageV(0, 0);
    __syncthreads();
    for (int kt = 0; kt < nkt; ++kt) {
      const int p = kt & 1;
      if (kt < nkt - 1) { stageK(p ^ 1, kt + 1); stageV(p ^ 1, kt + 1); }
      f32x4 sacc[4] = {};
      __builtin_amdgcn_s_setprio(1);
      #pragma unroll
      for (int ks = 0; ks < 4; ++ks)
        #pragma unroll
        for (int n = 0; n < 4; ++n) {
          int row = n * 16 + lr;
          s16x8 bk = *(const s16x8*)((const char*)Ks[p] + row * 256 +
                                     ((ks * 64 + lg * 16) ^ ((row & 7) << 4)));
          sacc[n] = mfma16(aq[ks], bk, sacc[n]);
        }
      __builtin_amdgcn_s_setprio(0);
      if (kt * 64 + 63 <= qwmin) {        // interior for this wave
        #pragma unroll
        for (int r = 0; r < 4; ++r) {
          int prow = wave * 16 + lg * 4 + r;
          #pragma unroll
          for (int n = 0; n < 4; ++n) {
            float p127 = rintf(exp2f(fmaf(sacc[n][r], c2, bias[r])));
            int col = n * 16 + lr;
            *(u16*)((char*)Ps + prow * 128 + ((col * 2) ^ ((prow & 7) << 4))) = f2bf(p127);
          }
        }
      } else {
        #pragma unroll
        for (int r = 0; r < 4; ++r) {
          int prow = wave * 16 + lg * 4 + r;
          int qg = qwmin + lg * 4 + r;
          #pragma unroll
          for (int n = 0; n < 4; ++n) {
            int kg = kt * 64 + n * 16 + lr;
            float a = fmaf(sacc[n][r], c2, bias[r]);
            float p127 = (kg <= qg) ? rintf(exp2f(a)) : 0.f;
            int col = n * 16 + lr;
            *(u16*)((char*)Ps + prow * 128 + ((col * 2) ^ ((prow & 7) << 4))) = f2bf(p127);
          }
        }
      }
      // Ps is wave-private: lgkmcnt orders ds_write -> ds_read, no barrier.
      __builtin_amdgcn_s_setprio(1);
      #pragma unroll
      for (int ks = 0; ks < 2; ++ks) {
        int prow = wave * 16 + lr;
        s16x8 ap = *(const s16x8*)((const char*)Ps + prow * 128 +
                                   ((ks * 64 + lg * 16) ^ ((prow & 7) << 4)));
        #pragma unroll
        for (int n = 0; n < 8; ++n) {
          int vrow = n * 16 + lr;
          s16x8 bv = *(const s16x8*)((const char*)Vs[p] + vrow * 128 +
                                     ((ks * 64 + lg * 16) ^ ((vrow & 7) << 4)));
          oacc[n] = mfma16(ap, bv, oacc[n]);
        }
      }
      __builtin_amdgcn_s_setprio(0);
      __syncthreads();  // drains this iter's stage loads; guards buffer reuse
    }
    const float pvs = sv * (1.0f / 127.0f);
    #pragma unroll
    for (int n = 0; n < 8; ++n)
      #pragma unroll
      for (int r = 0; r < 4; ++r) {
        float v = oacc[n][r] * pvs;
        gmax = fmaxf(gmax, fabsf(v));
        O[(size_t)(b * S_ + q0 + wave * 16 + lg * 4 + r) * HID + h * HD + n * 16 + lr] = v;
      }
  }
  atomic_absmax(omax, gmax, lane);
}

// ---------------------------------------------------------------------------
extern "C" void kernel_launch(void* const* d_in, const int* in_sizes, int n_in,
                              void* d_out, int out_size, void* d_ws, size_t ws_size,
                              hipStream_t stream) {
  const float* hs = (const float*)d_in[0];
  const float* Wq = (const float*)d_in[3];
  const float* Wk = (const float*)d_in[4];
  const float* Wv = (const float*)d_in[5];
  const float* Wo = (const float*)d_in[6];
  float* out = (float*)d_out;
  char* ws = (char*)d_ws;

  unsigned* sc = (unsigned*)ws;  // 0=x 1=Wq 2=Wk 3=Wv 4=Wo 5=q 6=k 7=v 8=attn_out
  size_t off = 256;
  u16* Xq = (u16*)(ws + off); off += (size_t)B_ * S_ * HID * 2;
  size_t wqb_off = off;
  u16* Wqb = (u16*)(ws + off); off += (size_t)HID * HID * 2;
  u16* Wkb = (u16*)(ws + off); off += (size_t)NKV * HD * HID * 2;
  u16* Wvb = (u16*)(ws + off); off += (size_t)NKV * HD * HID * 2;
  u16* Wob = (u16*)(ws + off); off += (size_t)HID * HID * 2;
  size_t qf_off = off;
  float* qf = (float*)(ws + off); off += (size_t)B_ * S_ * HID * 4;
  size_t kf_off = off;
  float* kf = (float*)(ws + off); off += (size_t)B_ * S_ * NKV * HD * 4;
  float* vf = (float*)(ws + off); off += (size_t)B_ * S_ * NKV * HD * 4;
  u16* qq = (u16*)(ws + off); off += (size_t)B_ * S_ * HID * 2;
  u16* kq = (u16*)(ws + off); off += (size_t)B_ * S_ * NKV * HD * 2;
  u16* vt = (u16*)(ws + off); off += (size_t)B_ * S_ * NKV * HD * 2;
  float2* tab = (float2*)(ws + off); off += (size_t)S_ * 64 * 8;
  float* attnf = (float*)(ws + qf_off);  // alias qf (dead after quantqk)
  u16* attnq = (u16*)(ws + wqb_off);     // alias Wqb (dead after gemm_qkv8)
  // split-K partials for O-proj: both regions dead by the time gemm_o8 runs
  // (attnf consumed by quant_k; kf..vt consumed by attn_k). 32MB each.
  float* P0 = (float*)(ws + qf_off);
  float* P1 = (float*)(ws + kf_off);  // kf+vf+qq+kq+vt span = 40MB >= 32MB

  hipFuncSetAttribute((const void*)gemm_qkv8,
                      hipFuncAttributeMaxDynamicSharedMemorySize, 131072);
  hipFuncSetAttribute((const void*)gemm_o8,
                      hipFuncAttributeMaxDynamicSharedMemorySize, 131072);

  hipMemsetAsync(sc, 0, 64, stream);

  dim3 blk(256);
  absmax5_k<<<dim3(416, 5), blk, 0, stream>>>(
      (const float4*)hs, (const float4*)Wq, (const float4*)Wk,
      (const float4*)Wv, (const float4*)Wo, sc);
  quant5_k<<<dim3(416, 5), blk, 0, stream>>>(
      (const float4*)hs, (const float4*)Wq, (const float4*)Wk,
      (const float4*)Wv, (const float4*)Wo,
      (u16x4*)Xq, (u16x4*)Wqb, (u16x4*)Wkb, (u16x4*)Wvb, (u16x4*)Wob, sc);
  rope_tab_k<<<256, blk, 0, stream>>>(tab);

  gemm_qkv8<<<192, 512, 131072, stream>>>(Xq, Wqb, Wkb, Wvb, qf, kf, vf, sc, sc + 7);

  rope2_k<<<dim3(512, 2), blk, 0, stream>>>(qf, kf, sc, tab);
  quantqk_k<<<dim3(512, 2), blk, 0, stream>>>((const float4*)qf, (const float4*)kf,
                                              (u16x4*)qq, (u16x4*)kq, sc);
  vquant_t_k<<<256, blk, 0, stream>>>(vf, (unsigned*)vt, sc);

  attn_k<<<256, 512, 0, stream>>>(qq, kq, vt, attnf, sc, sc + 8);

  quant_k<<<2048, blk, 0, stream>>>((const float4*)attnf, (u16x4*)attnq,
                                    B_ * S_ * HID / 4, sc, 8);
  gemm_o8<<<256, 512, 131072, stream>>>(attnq, Wob, P0, P1, sc);
  add_k<<<2048, blk, 0, stream>>>((const float4*)P0, (const float4*)P1,
                                  (float4*)out, B_ * S_ * HID / 4);
}

// Round 11
// 468.615 us; speedup vs baseline: 1.1907x; 1.1907x over previous
//
#include <hip/hip_runtime.h>
#include <math.h>

#define B_ 2
#define S_ 1024
#define HID 4096
#define NH 32
#define NKV 8
#define HD 128
#define LOG2E 1.44269504088896340736f

typedef short s16x8 __attribute__((ext_vector_type(8)));   // 8 bf16 (4 VGPRs)
typedef float f32x4 __attribute__((ext_vector_type(4)));
typedef int i32x4 __attribute__((ext_vector_type(4)));     // 16B / int32 acc
typedef unsigned short u16;
typedef u16 u16x4 __attribute__((ext_vector_type(4)));
typedef signed char s8;

__device__ __forceinline__ f32x4 mfma16(s16x8 a, s16x8 b, f32x4 c) {
  return __builtin_amdgcn_mfma_f32_16x16x32_bf16(a, b, c, 0, 0, 0);
}
__device__ __forceinline__ i32x4 mfma_i8(i32x4 a, i32x4 b, i32x4 c) {
  return __builtin_amdgcn_mfma_i32_16x16x64_i8(a, b, c, 0, 0, 0);
}
// exact for integer-valued floats |v| <= 127
__device__ __forceinline__ u16 f2bf(float f) {
  union { float f; unsigned u; } v; v.f = f;
  return (u16)(v.u >> 16);
}
__device__ __forceinline__ float get_scale(const unsigned* sc, int slot) {
  return fmaxf(__uint_as_float(sc[slot]) / 127.0f, 1e-8f);
}
__device__ __forceinline__ int q127(float x, float s) {
  return (int)fminf(fmaxf(rintf(x / s), -127.f), 127.f);
}
__device__ __forceinline__ unsigned pack4(float4 v, float s) {
  return (q127(v.x, s) & 255) | ((q127(v.y, s) & 255) << 8) |
         ((q127(v.z, s) & 255) << 16) | ((q127(v.w, s) & 255) << 24);
}
__device__ __forceinline__ void gload16(const void* g, void* l) {
  __builtin_amdgcn_global_load_lds(
      (const __attribute__((address_space(1))) unsigned*)g,
      (__attribute__((address_space(3))) unsigned*)l, 16, 0, 0);
}
__device__ __forceinline__ void atomic_absmax(unsigned* out, float m, int lane) {
  #pragma unroll
  for (int o = 32; o >= 1; o >>= 1) m = fmaxf(m, __shfl_xor(m, o));
  if (lane == 0) atomicMax(out, __float_as_uint(m));
}

#define SB_() __builtin_amdgcn_sched_barrier(0)
#define PBAR() do { SB_(); __builtin_amdgcn_s_barrier(); SB_(); } while (0)
#define VM6() do { SB_(); asm volatile("s_waitcnt vmcnt(6)" ::: "memory"); } while (0)
#define VM0() do { SB_(); asm volatile("s_waitcnt vmcnt(0)" ::: "memory"); } while (0)

// ---------------- fused absmax over the 5 input tensors ---------------------
__global__ void absmax5_k(const float4* __restrict__ p0, const float4* __restrict__ p1,
                          const float4* __restrict__ p2, const float4* __restrict__ p3,
                          const float4* __restrict__ p4, unsigned* __restrict__ sc) {
  int r = blockIdx.y;
  const float4* x; int n4;
  if (r == 0)      { x = p0; n4 = B_ * S_ * HID / 4; }
  else if (r == 1) { x = p1; n4 = HID * HID / 4; }
  else if (r == 2) { x = p2; n4 = NKV * HD * HID / 4; }
  else if (r == 3) { x = p3; n4 = NKV * HD * HID / 4; }
  else             { x = p4; n4 = HID * HID / 4; }
  float m = 0.f;
  int stride = gridDim.x * blockDim.x;
  for (int i = blockIdx.x * blockDim.x + threadIdx.x; i < n4; i += stride) {
    float4 v = x[i];
    m = fmaxf(m, fmaxf(fmaxf(fabsf(v.x), fabsf(v.y)), fmaxf(fabsf(v.z), fabsf(v.w))));
  }
  atomic_absmax(sc + r, m, threadIdx.x & 63);
}

// ---------------- fused quantize of the 5 input tensors -> s8 ---------------
__global__ void quant5_k(const float4* __restrict__ p0, const float4* __restrict__ p1,
                         const float4* __restrict__ p2, const float4* __restrict__ p3,
                         const float4* __restrict__ p4,
                         unsigned* __restrict__ y0, unsigned* __restrict__ y1,
                         unsigned* __restrict__ y2, unsigned* __restrict__ y3,
                         unsigned* __restrict__ y4, const unsigned* __restrict__ sc) {
  int r = blockIdx.y;
  const float4* x; unsigned* y; int n4;
  if (r == 0)      { x = p0; y = y0; n4 = B_ * S_ * HID / 4; }
  else if (r == 1) { x = p1; y = y1; n4 = HID * HID / 4; }
  else if (r == 2) { x = p2; y = y2; n4 = NKV * HD * HID / 4; }
  else if (r == 3) { x = p3; y = y3; n4 = NKV * HD * HID / 4; }
  else             { x = p4; y = y4; n4 = HID * HID / 4; }
  float s = get_scale(sc, r);
  int stride = gridDim.x * blockDim.x;
  for (int i = blockIdx.x * blockDim.x + threadIdx.x; i < n4; i += stride)
    y[i] = pack4(x[i], s);
}

// ---------------- generic quantize (attn output) -> s8 ----------------------
__global__ void quant_k(const float4* __restrict__ x, unsigned* __restrict__ y, int n4,
                        const unsigned* __restrict__ sc, int slot) {
  float s = get_scale(sc, slot);
  int stride = gridDim.x * blockDim.x;
  for (int i = blockIdx.x * blockDim.x + threadIdx.x; i < n4; i += stride)
    y[i] = pack4(x[i], s);
}

// ---------------- split-K reduce: out = P0 + P1 (scale pre-applied) ---------
__global__ void add_k(const float4* __restrict__ p0, const float4* __restrict__ p1,
                      float4* __restrict__ out, int n4) {
  int stride = gridDim.x * blockDim.x;
  for (int i = blockIdx.x * blockDim.x + threadIdx.x; i < n4; i += stride) {
    float4 a = p0[i], b = p1[i];
    out[i] = make_float4(a.x + b.x, a.y + b.y, a.z + b.z, a.w + b.w);
  }
}

// ============ 256x256 8-phase int8 GEMM (T2+T3+T4+T5) ========================
// C[M,N] = (A[M,k0:k0+nkt*128] * B^T) * scale.  s8 inputs, BK=128, int32
// accumulate (EXACT).  Byte geometry identical to the verified bf16 BK=64
// tile: 256 rows x 128B, ((row&7)<<4) swizzle, 16KB half-tiles, 2-gload STG,
// 8 waves (2M x 4N), vmcnt(6) at ph4/ph8, vmcnt(0) tail drain.  nkt even.
__device__ __forceinline__ void rdA(const s8* slot, int wm, int lr, int lg,
                                    i32x4 af[4][2]) {
  #pragma unroll
  for (int mi = 0; mi < 4; ++mi) {
    int row = wm * 64 + mi * 16 + lr;
    const char* base = (const char*)slot + row * 128;
    int sw = (row & 7) << 4;
    #pragma unroll
    for (int ks = 0; ks < 2; ++ks)
      af[mi][ks] = *(const i32x4*)(base + ((ks * 64 + lg * 16) ^ sw));
  }
}
__device__ __forceinline__ void rdB(const s8* slot, int wn, int lr, int lg,
                                    i32x4 bf[2][2]) {
  #pragma unroll
  for (int ni = 0; ni < 2; ++ni) {
    int row = wn * 32 + ni * 16 + lr;
    const char* base = (const char*)slot + row * 128;
    int sw = (row & 7) << 4;
    #pragma unroll
    for (int ks = 0; ks < 2; ++ks)
      bf[ni][ks] = *(const i32x4*)(base + ((ks * 64 + lg * 16) ^ sw));
  }
}
template <int PM, int PN>
__device__ __forceinline__ void mfma_phase(i32x4 (&acc)[2][2][4][2],
                                           const i32x4 (&af)[4][2],
                                           const i32x4 (&bf)[2][2]) {
  __builtin_amdgcn_s_setprio(1);
  #pragma unroll
  for (int mi = 0; mi < 4; ++mi)
    #pragma unroll
    for (int ni = 0; ni < 2; ++ni)
      #pragma unroll
      for (int ks = 0; ks < 2; ++ks)
        acc[PM][PN][mi][ni] = mfma_i8(af[mi][ks], bf[ni][ks], acc[PM][PN][mi][ni]);
  __builtin_amdgcn_s_setprio(0);
}

__device__ void gemm256(const s8* __restrict__ A, const s8* __restrict__ Bm,
                        float* __restrict__ C, int Ncols, int m0, int n0,
                        int k0, int nkt, float scale, unsigned* omax, s8* S) {
  const int tid = threadIdx.x;
  const int wave = tid >> 6, lane = tid & 63;
  const int lr = lane & 15, lg = lane >> 4;
  const int wm = wave >> 2, wn = wave & 3;
  s8* SA00 = S;          s8* SA01 = S + 16384;
  s8* SB00 = S + 32768;  s8* SB01 = S + 49152;
  s8* SA10 = S + 65536;  s8* SA11 = S + 81920;
  s8* SB10 = S + 98304;  s8* SB11 = S + 114688;
  // staging: thread t covers rows r0, r0+64 at pre-swizzled byte col ce
  const int r0 = tid >> 3;
  const int ce = ((tid & 7) * 16) ^ ((r0 & 7) << 4);
  const s8* pa0 = A + (size_t)(m0 + r0) * HID + k0 + ce;
  const s8* pa1 = pa0 + (size_t)128 * HID;
  const s8* pb0 = Bm + (size_t)(n0 + r0) * HID + k0 + ce;
  const s8* pb1 = pb0 + (size_t)128 * HID;
  const int wdst = wave * 1024;
  i32x4 acc[2][2][4][2] = {};
  i32x4 af[4][2], bf[2][2];

  auto STG = [&](const s8* p, s8* slot, int tcol) {
    const s8* g = p + tcol * 128;
    gload16(g, slot + wdst);
    gload16(g + (size_t)64 * HID, slot + 8192 + wdst);
  };

  // prologue: tile0 complete + 3 half-tiles of tile1 in flight
  STG(pa0, SA00, 0); STG(pb0, SB00, 0); STG(pa1, SA01, 0); STG(pb1, SB01, 0);
  STG(pa0, SA10, 1); STG(pb1, SB11, 1); STG(pa1, SA11, 1);
  VM6(); PBAR();

  #pragma unroll 1
  for (int t = 0; t < nkt; t += 2) {
    const bool g2 = t + 2 < nkt, g3 = t + 3 < nkt;
    // ph1 (0,0) on tile t (buf0)
    rdA(SA00, wm, lr, lg, af); rdB(SB00, wn, lr, lg, bf);
    STG(pb0, SB10, t + 1);
    PBAR(); mfma_phase<0, 0>(acc, af, bf); PBAR();
    // ph2 (0,1)
    rdB(SB01, wn, lr, lg, bf);
    if (g2) STG(pa0, SA00, t + 2);
    PBAR(); mfma_phase<0, 1>(acc, af, bf); PBAR();
    // ph3 (1,1)
    rdA(SA01, wm, lr, lg, af);
    if (g2) STG(pb1, SB01, t + 2);
    PBAR(); mfma_phase<1, 1>(acc, af, bf); PBAR();
    // ph4 (1,0)
    rdB(SB00, wn, lr, lg, bf);
    if (g2) STG(pa1, SA01, t + 2);
    PBAR(); mfma_phase<1, 0>(acc, af, bf);
    if (g2) { VM6(); } else { VM0(); }  // tail: drain last-tile stages fully
    PBAR();
    // ph5 (0,0) on tile t+1 (buf1)
    rdA(SA10, wm, lr, lg, af); rdB(SB10, wn, lr, lg, bf);
    if (g2) STG(pb0, SB00, t + 2);
    PBAR(); mfma_phase<0, 0>(acc, af, bf); PBAR();
    // ph6 (0,1)
    rdB(SB11, wn, lr, lg, bf);
    if (g3) STG(pa0, SA10, t + 3);
    PBAR(); mfma_phase<0, 1>(acc, af, bf); PBAR();
    // ph7 (1,1)
    rdA(SA11, wm, lr, lg, af);
    if (g3) STG(pb1, SB11, t + 3);
    PBAR(); mfma_phase<1, 1>(acc, af, bf); PBAR();
    // ph8 (1,0)
    rdB(SB10, wn, lr, lg, bf);
    if (g3) STG(pa1, SA11, t + 3);
    PBAR(); mfma_phase<1, 0>(acc, af, bf); VM6(); PBAR();
  }

  float gm = 0.f;
  #pragma unroll
  for (int mh = 0; mh < 2; ++mh)
    #pragma unroll
    for (int nh = 0; nh < 2; ++nh)
      #pragma unroll
      for (int mi = 0; mi < 4; ++mi)
        #pragma unroll
        for (int ni = 0; ni < 2; ++ni) {
          size_t rbase = (size_t)(m0 + mh * 128 + wm * 64 + mi * 16 + lg * 4);
          int cb = n0 + nh * 128 + wn * 32 + ni * 16 + lr;
          #pragma unroll
          for (int r = 0; r < 4; ++r) {
            float v = (float)acc[mh][nh][mi][ni][r] * scale;
            gm = fmaxf(gm, fabsf(v));
            C[(rbase + r) * (size_t)Ncols + cb] = v;
          }
        }
  if (omax) atomic_absmax(omax, gm, lane);
}

// fused Q/K/V projection: 192 blocks (8 M-tiles x 24 N-tiles), XCD-swizzled
__global__ __launch_bounds__(512, 1) void gemm_qkv8(
    const s8* __restrict__ Xq, const s8* __restrict__ Wqb,
    const s8* __restrict__ Wkb, const s8* __restrict__ Wvb,
    float* __restrict__ qf, float* __restrict__ kf, float* __restrict__ vf,
    const unsigned* __restrict__ sc, unsigned* __restrict__ vmax) {
  extern __shared__ __align__(16) s8 S[];
  int raw = blockIdx.x;
  int wg = (raw & 7) * 24 + (raw >> 3);
  int bx = wg & 7, by = wg >> 3;
  const s8* Bm; float* C; int Ncols, n0, sslot; unsigned* om = nullptr;
  if (by < 16)      { Bm = Wqb; C = qf; Ncols = HID;      n0 = by * 256;        sslot = 1; }
  else if (by < 20) { Bm = Wkb; C = kf; Ncols = NKV * HD; n0 = (by - 16) * 256; sslot = 2; }
  else              { Bm = Wvb; C = vf; Ncols = NKV * HD; n0 = (by - 20) * 256; sslot = 3; om = vmax; }
  float scale = get_scale(sc, 0) * get_scale(sc, sslot);
  gemm256(Xq, Bm, C, Ncols, bx * 256, n0, 0, 32, scale, om, S);
}

// O projection, split-K=2: 256 blocks (128 tiles x 2 K-halves), XCD-swizzled
__global__ __launch_bounds__(512, 1) void gemm_o8(
    const s8* __restrict__ A, const s8* __restrict__ Bm,
    float* __restrict__ P0, float* __restrict__ P1,
    const unsigned* __restrict__ sc) {
  extern __shared__ __align__(16) s8 S[];
  int raw = blockIdx.x;
  int wg = (raw & 7) * 32 + (raw >> 3);   // 256 = 8 XCD x 32, bijective
  int tile = wg >> 1, half = wg & 1;
  int by = tile & 15, bx = tile >> 4;
  float scale = get_scale(sc, 8) * get_scale(sc, 4);
  gemm256(A, Bm, half ? P1 : P0, HID, bx * 256, by * 256, half * 2048, 16,
          scale, nullptr, S);
}

// ---------------- RoPE cos/sin table (pos x 64) -----------------------------
__global__ void rope_tab_k(float2* __restrict__ tab) {
  int i = blockIdx.x * 256 + threadIdx.x;  // 65536
  int pos = i >> 6, d = i & 63;
  float inv = exp2f((float)d * (-13.287712379549449f / 64.0f));
  float ang = (float)pos * inv;
  tab[i] = make_float2(cosf(ang), sinf(ang));
}

// ---------------- RoPE in-place + absmax, q & k fused -----------------------
__global__ void rope2_k(float* __restrict__ qf, float* __restrict__ kf,
                        unsigned* __restrict__ sc, const float2* __restrict__ tab) {
  int reg = blockIdx.y;
  float* q = reg ? kf : qf;
  int nheads = reg ? NKV : NH;
  unsigned* om = sc + (reg ? 6 : 5);
  int total = B_ * S_ * nheads * 64;
  int stride = gridDim.x * blockDim.x;
  float m = 0.f;
  for (int i = blockIdx.x * blockDim.x + threadIdx.x; i < total; i += stride) {
    int d = i & 63;
    int h = (i >> 6) % nheads;
    int bs = i / (64 * nheads);
    int pos = bs & (S_ - 1);
    float2 cs = tab[(pos << 6) + d];
    size_t base = ((size_t)bs * nheads + h) * HD + d;
    float x1 = q[base], x2 = q[base + 64];
    float o1 = x1 * cs.x - x2 * cs.y;
    float o2 = x2 * cs.x + x1 * cs.y;
    q[base] = o1; q[base + 64] = o2;
    m = fmaxf(m, fmaxf(fabsf(o1), fabsf(o2)));
  }
  atomic_absmax(om, m, threadIdx.x & 63);
}

// ---------------- quantize q & k fused (bf16 for attn) ----------------------
__global__ void quantqk_k(const float4* __restrict__ qf, const float4* __restrict__ kf,
                          u16x4* __restrict__ qq, u16x4* __restrict__ kq,
                          const unsigned* __restrict__ sc) {
  int reg = blockIdx.y;
  const float4* x = reg ? kf : qf;
  u16x4* y = reg ? kq : qq;
  int n4 = reg ? (B_ * S_ * NKV * HD / 4) : (B_ * S_ * HID / 4);
  float s = get_scale(sc, reg ? 6 : 5);
  int stride = gridDim.x * blockDim.x;
  for (int i = blockIdx.x * blockDim.x + threadIdx.x; i < n4; i += stride) {
    float4 v = x[i];
    u16x4 o;
    o[0] = f2bf(fminf(fmaxf(rintf(v.x / s), -127.f), 127.f));
    o[1] = f2bf(fminf(fmaxf(rintf(v.y / s), -127.f), 127.f));
    o[2] = f2bf(fminf(fmaxf(rintf(v.z / s), -127.f), 127.f));
    o[3] = f2bf(fminf(fmaxf(rintf(v.w / s), -127.f), 127.f));
    y[i] = o;
  }
}

// ---------------- V: quantize + transpose to (B,NKV,HD,S), LDS-tiled --------
__global__ __launch_bounds__(256) void vquant_t_k(const float* __restrict__ vf,
                                                  unsigned* __restrict__ vtw,
                                                  const unsigned* __restrict__ sc) {
  __shared__ u16 Ls[64 * 132];
  float s = get_scale(sc, 7);
  int st = blockIdx.x & 15, kvh = (blockIdx.x >> 4) & 7, b = blockIdx.x >> 7;
  int s0 = st * 64;
  #pragma unroll
  for (int i = 0; i < 8; ++i) {
    int o = i * 256 + threadIdx.x;
    int sr = o >> 5, c4 = o & 31;
    float4 v = *(const float4*)(vf + ((size_t)(b * S_ + s0 + sr)) * (NKV * HD) +
                                kvh * HD + c4 * 4);
    u16x4 w;
    w[0] = f2bf(fminf(fmaxf(rintf(v.x / s), -127.f), 127.f));
    w[1] = f2bf(fminf(fmaxf(rintf(v.y / s), -127.f), 127.f));
    w[2] = f2bf(fminf(fmaxf(rintf(v.z / s), -127.f), 127.f));
    w[3] = f2bf(fminf(fmaxf(rintf(v.w / s), -127.f), 127.f));
    *(u16x4*)(Ls + sr * 132 + c4 * 4) = w;
  }
  __syncthreads();
  #pragma unroll
  for (int i = 0; i < 16; ++i) {
    int o = i * 256 + threadIdx.x;
    int d = o >> 5, sj = o & 31;
    unsigned lo = Ls[(sj * 2) * 132 + d], hi = Ls[(sj * 2 + 1) * 132 + d];
    vtw[(((size_t)(b * NKV + kvh) * HD + d) << 9) + st * 32 + sj] = lo | (hi << 16);
  }
}

// ---------------- two-pass quantized causal GQA attention (bf16) ------------
__global__ __launch_bounds__(512) void attn_k(
    const u16* __restrict__ Q, const u16* __restrict__ Kq, const u16* __restrict__ Vt,
    float* __restrict__ O, const unsigned* __restrict__ sc, unsigned* __restrict__ omax) {
  __shared__ __align__(16) u16 Ks[2][64 * 128];
  __shared__ __align__(16) u16 Vs[2][128 * 64];
  __shared__ __align__(16) u16 Ps[128 * 64];
  const int tid = threadIdx.x;
  const int wave = tid >> 6, lane = tid & 63;
  const int lr = lane & 15, lg = lane >> 4;
  const int raw = blockIdx.x;
  const int xcd = raw & 7, j = raw >> 3;
  const int grp = xcd + 8 * (j >> 4);
  const int within = j & 15;
  const int b = grp >> 3, kvh = grp & 7;
  const int h = kvh * 4 + (within >> 2);
  const int qp = within & 3;
  const float sq = get_scale(sc, 5), sk = get_scale(sc, 6), sv = get_scale(sc, 7);
  const float c2 = sq * sk * 0.08838834764831845f * LOG2E;
  const float M0 = 32.0f;
  const int k_rin = lane >> 4;
  const int k_cb0 = (lane & 15) * 16;
  const int v_rin = lane >> 3;
  const int v_cb = ((lane & 7) * 16) ^ ((v_rin & 7) << 4);
  float gmax = 0.f;

  auto stageK = [&](int buf, int kt) {
    #pragma unroll
    for (int i = 0; i < 2; ++i) {
      int ch = wave * 2 + i;
      int row = ch * 4 + k_rin;
      int cb = k_cb0 ^ ((row & 7) << 4);
      gload16(Kq + (size_t)(b * S_ + kt * 64 + row) * (NKV * HD) + kvh * HD + (cb >> 1),
              Ks[buf] + ch * 512);
    }
  };
  auto stageV = [&](int buf, int kt) {
    #pragma unroll
    for (int i = 0; i < 2; ++i) {
      int ch = wave * 2 + i;
      int vrow = ch * 8 + v_rin;
      gload16(Vt + ((size_t)(b * NKV + kvh) * HD + vrow) * S_ + kt * 64 + (v_cb >> 1),
              Vs[buf] + ch * 512);
    }
  };

  for (int pi = 0; pi < 2; ++pi) {
    const int qt = pi ? 7 - qp : qp;
    const int q0 = qt * 128;
    const int nkt = 2 * (qt + 1);
    const int qwmin = q0 + wave * 16;
    s16x8 aq[4];
    {
      const u16* qp_ = Q + (size_t)(b * S_ + q0 + wave * 16 + lr) * HID + h * HD + lg * 8;
      #pragma unroll
      for (int ks = 0; ks < 4; ++ks) aq[ks] = *(const s16x8*)(qp_ + ks * 32);
    }
    float ll[4] = {0.f, 0.f, 0.f, 0.f};

    // ---- pass 1: denominator only, fixed reference M0 ----
    stageK(0, 0);
    __syncthreads();
    for (int kt = 0; kt < nkt; ++kt) {
      const int p = kt & 1;
      if (kt < nkt - 1) stageK(p ^ 1, kt + 1);
      f32x4 sacc[4] = {};
      __builtin_amdgcn_s_setprio(1);
      #pragma unroll
      for (int ks = 0; ks < 4; ++ks)
        #pragma unroll
        for (int n = 0; n < 4; ++n) {
          int row = n * 16 + lr;
          s16x8 bk = *(const s16x8*)((const char*)Ks[p] + row * 256 +
                                     ((ks * 64 + lg * 16) ^ ((row & 7) << 4)));
          sacc[n] = mfma16(aq[ks], bk, sacc[n]);
        }
      __builtin_amdgcn_s_setprio(0);
      if (kt * 64 + 63 <= qwmin) {
        #pragma unroll
        for (int r = 0; r < 4; ++r)
          #pragma unroll
          for (int n = 0; n < 4; ++n)
            ll[r] += exp2f(fmaf(sacc[n][r], c2, -M0));
      } else {
        #pragma unroll
        for (int r = 0; r < 4; ++r) {
          int qg = qwmin + lg * 4 + r;
          #pragma unroll
          for (int n = 0; n < 4; ++n) {
            int kg = kt * 64 + n * 16 + lr;
            float e = exp2f(fmaf(sacc[n][r], c2, -M0));
            ll[r] += (kg <= qg) ? e : 0.f;
          }
        }
      }
      __syncthreads();
    }
    float bias[4];
    #pragma unroll
    for (int r = 0; r < 4; ++r) {
      float l = ll[r];
      #pragma unroll
      for (int o = 8; o >= 1; o >>= 1) l += __shfl_xor(l, o);
      bias[r] = 6.9886846867721655f - __log2f(l) - M0;  // log2(127) - log2(l) - M0
    }

    // ---- pass 2: recompute S, quantize P, PV ----
    f32x4 oacc[8] = {};
    stageK(0, 0); stageV(0, 0);
    __syncthreads();
    for (int kt = 0; kt < nkt; ++kt) {
      const int p = kt & 1;
      if (kt < nkt - 1) { stageK(p ^ 1, kt + 1); stageV(p ^ 1, kt + 1); }
      f32x4 sacc[4] = {};
      __builtin_amdgcn_s_setprio(1);
      #pragma unroll
      for (int ks = 0; ks < 4; ++ks)
        #pragma unroll
        for (int n = 0; n < 4; ++n) {
          int row = n * 16 + lr;
          s16x8 bk = *(const s16x8*)((const char*)Ks[p] + row * 256 +
                                     ((ks * 64 + lg * 16) ^ ((row & 7) << 4)));
          sacc[n] = mfma16(aq[ks], bk, sacc[n]);
        }
      __builtin_amdgcn_s_setprio(0);
      if (kt * 64 + 63 <= qwmin) {
        #pragma unroll
        for (int r = 0; r < 4; ++r) {
          int prow = wave * 16 + lg * 4 + r;
          #pragma unroll
          for (int n = 0; n < 4; ++n) {
            float p127 = rintf(exp2f(fmaf(sacc[n][r], c2, bias[r])));
            int col = n * 16 + lr;
            *(u16*)((char*)Ps + prow * 128 + ((col * 2) ^ ((prow & 7) << 4))) = f2bf(p127);
          }
        }
      } else {
        #pragma unroll
        for (int r = 0; r < 4; ++r) {
          int prow = wave * 16 + lg * 4 + r;
          int qg = qwmin + lg * 4 + r;
          #pragma unroll
          for (int n = 0; n < 4; ++n) {
            int kg = kt * 64 + n * 16 + lr;
            float a = fmaf(sacc[n][r], c2, bias[r]);
            float p127 = (kg <= qg) ? rintf(exp2f(a)) : 0.f;
            int col = n * 16 + lr;
            *(u16*)((char*)Ps + prow * 128 + ((col * 2) ^ ((prow & 7) << 4))) = f2bf(p127);
          }
        }
      }
      __builtin_amdgcn_s_setprio(1);
      #pragma unroll
      for (int ks = 0; ks < 2; ++ks) {
        int prow = wave * 16 + lr;
        s16x8 ap = *(const s16x8*)((const char*)Ps + prow * 128 +
                                   ((ks * 64 + lg * 16) ^ ((prow & 7) << 4)));
        #pragma unroll
        for (int n = 0; n < 8; ++n) {
          int vrow = n * 16 + lr;
          s16x8 bv = *(const s16x8*)((const char*)Vs[p] + vrow * 128 +
                                     ((ks * 64 + lg * 16) ^ ((vrow & 7) << 4)));
          oacc[n] = mfma16(ap, bv, oacc[n]);
        }
      }
      __builtin_amdgcn_s_setprio(0);
      __syncthreads();
    }
    const float pvs = sv * (1.0f / 127.0f);
    #pragma unroll
    for (int n = 0; n < 8; ++n)
      #pragma unroll
      for (int r = 0; r < 4; ++r) {
        float v = oacc[n][r] * pvs;
        gmax = fmaxf(gmax, fabsf(v));
        O[(size_t)(b * S_ + q0 + wave * 16 + lg * 4 + r) * HID + h * HD + n * 16 + lr] = v;
      }
  }
  atomic_absmax(omax, gmax, lane);
}

// ---------------------------------------------------------------------------
extern "C" void kernel_launch(void* const* d_in, const int* in_sizes, int n_in,
                              void* d_out, int out_size, void* d_ws, size_t ws_size,
                              hipStream_t stream) {
  const float* hs = (const float*)d_in[0];
  const float* Wq = (const float*)d_in[3];
  const float* Wk = (const float*)d_in[4];
  const float* Wv = (const float*)d_in[5];
  const float* Wo = (const float*)d_in[6];
  float* out = (float*)d_out;
  char* ws = (char*)d_ws;

  unsigned* sc = (unsigned*)ws;  // 0=x 1=Wq 2=Wk 3=Wv 4=Wo 5=q 6=k 7=v 8=attn_out
  size_t off = 256;
  s8* Xq = (s8*)(ws + off); off += (size_t)B_ * S_ * HID;          // 8MB
  size_t wqb_off = off;
  s8* Wqb = (s8*)(ws + off); off += (size_t)HID * HID;             // 16MB
  s8* Wkb = (s8*)(ws + off); off += (size_t)NKV * HD * HID;        // 4MB
  s8* Wvb = (s8*)(ws + off); off += (size_t)NKV * HD * HID;        // 4MB
  s8* Wob = (s8*)(ws + off); off += (size_t)HID * HID;             // 16MB
  size_t qf_off = off;
  float* qf = (float*)(ws + off); off += (size_t)B_ * S_ * HID * 4;       // 32MB
  size_t kf_off = off;
  float* kf = (float*)(ws + off); off += (size_t)B_ * S_ * NKV * HD * 4;  // 8MB
  float* vf = (float*)(ws + off); off += (size_t)B_ * S_ * NKV * HD * 4;  // 8MB
  u16* qq = (u16*)(ws + off); off += (size_t)B_ * S_ * HID * 2;           // 16MB
  u16* kq = (u16*)(ws + off); off += (size_t)B_ * S_ * NKV * HD * 2;      // 4MB
  u16* vt = (u16*)(ws + off); off += (size_t)B_ * S_ * NKV * HD * 2;      // 4MB
  float2* tab = (float2*)(ws + off); off += (size_t)S_ * 64 * 8;
  float* attnf = (float*)(ws + qf_off);  // alias qf (dead after quantqk)
  s8* attnq = (s8*)(ws + wqb_off);       // alias Wqb (dead after gemm_qkv8)
  // split-K partials for O-proj: both regions dead by the time gemm_o8 runs
  // (attnf consumed by quant_k; kf..vt consumed by attn_k). 32MB each.
  float* P0 = (float*)(ws + qf_off);
  float* P1 = (float*)(ws + kf_off);  // kf+vf+qq+kq+vt span = 40MB >= 32MB

  hipFuncSetAttribute((const void*)gemm_qkv8,
                      hipFuncAttributeMaxDynamicSharedMemorySize, 131072);
  hipFuncSetAttribute((const void*)gemm_o8,
                      hipFuncAttributeMaxDynamicSharedMemorySize, 131072);

  hipMemsetAsync(sc, 0, 64, stream);

  dim3 blk(256);
  absmax5_k<<<dim3(416, 5), blk, 0, stream>>>(
      (const float4*)hs, (const float4*)Wq, (const float4*)Wk,
      (const float4*)Wv, (const float4*)Wo, sc);
  quant5_k<<<dim3(416, 5), blk, 0, stream>>>(
      (const float4*)hs, (const float4*)Wq, (const float4*)Wk,
      (const float4*)Wv, (const float4*)Wo,
      (unsigned*)Xq, (unsigned*)Wqb, (unsigned*)Wkb, (unsigned*)Wvb,
      (unsigned*)Wob, sc);
  rope_tab_k<<<256, blk, 0, stream>>>(tab);

  gemm_qkv8<<<192, 512, 131072, stream>>>(Xq, Wqb, Wkb, Wvb, qf, kf, vf, sc, sc + 7);

  rope2_k<<<dim3(512, 2), blk, 0, stream>>>(qf, kf, sc, tab);
  quantqk_k<<<dim3(512, 2), blk, 0, stream>>>((const float4*)qf, (const float4*)kf,
                                              (u16x4*)qq, (u16x4*)kq, sc);
  vquant_t_k<<<256, blk, 0, stream>>>(vf, (unsigned*)vt, sc);

  attn_k<<<256, 512, 0, stream>>>(qq, kq, vt, attnf, sc, sc + 8);

  quant_k<<<2048, blk, 0, stream>>>((const float4*)attnf, (unsigned*)attnq,
                                    B_ * S_ * HID / 4, sc, 8);
  gemm_o8<<<256, 512, 131072, stream>>>(attnq, Wob, P0, P1, sc);
  add_k<<<2048, blk, 0, stream>>>((const float4*)P0, (const float4*)P1,
                                  (float4*)out, B_ * S_ * HID / 4);
}

// Round 12
// 459.842 us; speedup vs baseline: 1.2134x; 1.0191x over previous
//
#include <hip/hip_runtime.h>
#include <math.h>

#define B_ 2
#define S_ 1024
#define HID 4096
#define NH 32
#define NKV 8
#define HD 128
#define LOG2E 1.44269504088896340736f

typedef short s16x8 __attribute__((ext_vector_type(8)));   // 8 bf16 (4 VGPRs)
typedef float f32x4 __attribute__((ext_vector_type(4)));
typedef int i32x4 __attribute__((ext_vector_type(4)));     // 16B / int32 acc
typedef unsigned short u16;
typedef u16 u16x4 __attribute__((ext_vector_type(4)));
typedef signed char s8;

__device__ __forceinline__ f32x4 mfma16(s16x8 a, s16x8 b, f32x4 c) {
  return __builtin_amdgcn_mfma_f32_16x16x32_bf16(a, b, c, 0, 0, 0);
}
__device__ __forceinline__ i32x4 mfma_i8(i32x4 a, i32x4 b, i32x4 c) {
  return __builtin_amdgcn_mfma_i32_16x16x64_i8(a, b, c, 0, 0, 0);
}
// exact for integer-valued floats |v| <= 127
__device__ __forceinline__ u16 f2bf(float f) {
  union { float f; unsigned u; } v; v.f = f;
  return (u16)(v.u >> 16);
}
__device__ __forceinline__ float get_scale(const unsigned* sc, int slot) {
  return fmaxf(__uint_as_float(sc[slot]) / 127.0f, 1e-8f);
}
__device__ __forceinline__ int q127(float x, float s) {
  return (int)fminf(fmaxf(rintf(x / s), -127.f), 127.f);
}
__device__ __forceinline__ unsigned pack4(float4 v, float s) {
  return (q127(v.x, s) & 255) | ((q127(v.y, s) & 255) << 8) |
         ((q127(v.z, s) & 255) << 16) | ((q127(v.w, s) & 255) << 24);
}
__device__ __forceinline__ float max4(float4 v) {
  return fmaxf(fmaxf(fabsf(v.x), fabsf(v.y)), fmaxf(fabsf(v.z), fabsf(v.w)));
}
__device__ __forceinline__ void gload16(const void* g, void* l) {
  __builtin_amdgcn_global_load_lds(
      (const __attribute__((address_space(1))) unsigned*)g,
      (__attribute__((address_space(3))) unsigned*)l, 16, 0, 0);
}
__device__ __forceinline__ void atomic_absmax(unsigned* out, float m, int lane) {
  #pragma unroll
  for (int o = 32; o >= 1; o >>= 1) m = fmaxf(m, __shfl_xor(m, o));
  if (lane == 0) atomicMax(out, __float_as_uint(m));
}

#define SB_() __builtin_amdgcn_sched_barrier(0)
#define PBAR() do { SB_(); __builtin_amdgcn_s_barrier(); SB_(); } while (0)
#define VM6() do { SB_(); asm volatile("s_waitcnt vmcnt(6)" ::: "memory"); } while (0)
#define VM0() do { SB_(); asm volatile("s_waitcnt vmcnt(0)" ::: "memory"); } while (0)

// work-proportional block partition for the 5 input tensors (2:4:1:1:4 /12
// of 2048 blocks) -> per-thread work equalized across tensors.
__device__ __forceinline__ void tensor_pick(int blk, int& r, int& b0, int& nb) {
  if (blk < 342)       { r = 0; b0 = 0;    nb = 342; }
  else if (blk < 1024) { r = 1; b0 = 342;  nb = 682; }
  else if (blk < 1195) { r = 2; b0 = 1024; nb = 171; }
  else if (blk < 1366) { r = 3; b0 = 1195; nb = 171; }
  else                 { r = 4; b0 = 1366; nb = 682; }
}

// ---------------- fused absmax over the 5 input tensors ---------------------
// 4-way unrolled independent loads (MLP) + balanced partition.
__global__ void absmax5_k(const float4* __restrict__ p0, const float4* __restrict__ p1,
                          const float4* __restrict__ p2, const float4* __restrict__ p3,
                          const float4* __restrict__ p4, unsigned* __restrict__ sc) {
  int r, b0, nb;
  tensor_pick(blockIdx.x, r, b0, nb);
  const float4* x; int n4;
  if (r == 0)      { x = p0; n4 = B_ * S_ * HID / 4; }
  else if (r == 1) { x = p1; n4 = HID * HID / 4; }
  else if (r == 2) { x = p2; n4 = NKV * HD * HID / 4; }
  else if (r == 3) { x = p3; n4 = NKV * HD * HID / 4; }
  else             { x = p4; n4 = HID * HID / 4; }
  const int stride = nb * 256;
  int i = (blockIdx.x - b0) * 256 + threadIdx.x;
  float m0 = 0.f, m1 = 0.f, m2 = 0.f, m3 = 0.f;
  for (; i + 3 * stride < n4; i += 4 * stride) {
    float4 v0 = x[i], v1 = x[i + stride], v2 = x[i + 2 * stride], v3 = x[i + 3 * stride];
    m0 = fmaxf(m0, max4(v0)); m1 = fmaxf(m1, max4(v1));
    m2 = fmaxf(m2, max4(v2)); m3 = fmaxf(m3, max4(v3));
  }
  for (; i < n4; i += stride) m0 = fmaxf(m0, max4(x[i]));
  float m = fmaxf(fmaxf(m0, m1), fmaxf(m2, m3));
  atomic_absmax(sc + r, m, threadIdx.x & 63);
}

// ---------------- fused quantize of the 5 input tensors -> s8 ---------------
__global__ void quant5_k(const float4* __restrict__ p0, const float4* __restrict__ p1,
                         const float4* __restrict__ p2, const float4* __restrict__ p3,
                         const float4* __restrict__ p4,
                         unsigned* __restrict__ y0, unsigned* __restrict__ y1,
                         unsigned* __restrict__ y2, unsigned* __restrict__ y3,
                         unsigned* __restrict__ y4, const unsigned* __restrict__ sc) {
  int r, b0, nb;
  tensor_pick(blockIdx.x, r, b0, nb);
  const float4* x; unsigned* y; int n4;
  if (r == 0)      { x = p0; y = y0; n4 = B_ * S_ * HID / 4; }
  else if (r == 1) { x = p1; y = y1; n4 = HID * HID / 4; }
  else if (r == 2) { x = p2; y = y2; n4 = NKV * HD * HID / 4; }
  else if (r == 3) { x = p3; y = y3; n4 = NKV * HD * HID / 4; }
  else             { x = p4; y = y4; n4 = HID * HID / 4; }
  float s = get_scale(sc, r);
  const int stride = nb * 256;
  int i = (blockIdx.x - b0) * 256 + threadIdx.x;
  for (; i + 3 * stride < n4; i += 4 * stride) {
    float4 v0 = x[i], v1 = x[i + stride], v2 = x[i + 2 * stride], v3 = x[i + 3 * stride];
    y[i] = pack4(v0, s);
    y[i + stride] = pack4(v1, s);
    y[i + 2 * stride] = pack4(v2, s);
    y[i + 3 * stride] = pack4(v3, s);
  }
  for (; i < n4; i += stride) y[i] = pack4(x[i], s);
}

// ---------------- generic quantize (attn output) -> s8, 4-way MLP -----------
__global__ void quant_k(const float4* __restrict__ x, unsigned* __restrict__ y, int n4,
                        const unsigned* __restrict__ sc, int slot) {
  float s = get_scale(sc, slot);
  int stride = gridDim.x * blockDim.x;
  int i = blockIdx.x * blockDim.x + threadIdx.x;
  for (; i + 3 * stride < n4; i += 4 * stride) {
    float4 v0 = x[i], v1 = x[i + stride], v2 = x[i + 2 * stride], v3 = x[i + 3 * stride];
    y[i] = pack4(v0, s);
    y[i + stride] = pack4(v1, s);
    y[i + 2 * stride] = pack4(v2, s);
    y[i + 3 * stride] = pack4(v3, s);
  }
  for (; i < n4; i += stride) y[i] = pack4(x[i], s);
}

// ---------------- split-K reduce: out = P0 + P1, 2-way MLP ------------------
__global__ void add_k(const float4* __restrict__ p0, const float4* __restrict__ p1,
                      float4* __restrict__ out, int n4) {
  int stride = gridDim.x * blockDim.x;
  int i = blockIdx.x * blockDim.x + threadIdx.x;
  for (; i + stride < n4; i += 2 * stride) {
    float4 a0 = p0[i], b0 = p1[i], a1 = p0[i + stride], b1 = p1[i + stride];
    out[i] = make_float4(a0.x + b0.x, a0.y + b0.y, a0.z + b0.z, a0.w + b0.w);
    out[i + stride] = make_float4(a1.x + b1.x, a1.y + b1.y, a1.z + b1.z, a1.w + b1.w);
  }
  for (; i < n4; i += stride) {
    float4 a = p0[i], b = p1[i];
    out[i] = make_float4(a.x + b.x, a.y + b.y, a.z + b.z, a.w + b.w);
  }
}

// ============ 256x256 8-phase int8 GEMM (T2+T3+T4+T5) ========================
// C[M,N] = (A[M,k0:k0+nkt*128] * B^T) * scale.  s8 inputs, BK=128, int32
// accumulate (EXACT).  Byte geometry identical to the verified bf16 BK=64
// tile: 256 rows x 128B, ((row&7)<<4) swizzle, 16KB half-tiles, 2-gload STG,
// 8 waves (2M x 4N), vmcnt(6) at ph4/ph8, vmcnt(0) tail drain.  nkt even.
__device__ __forceinline__ void rdA(const s8* slot, int wm, int lr, int lg,
                                    i32x4 af[4][2]) {
  #pragma unroll
  for (int mi = 0; mi < 4; ++mi) {
    int row = wm * 64 + mi * 16 + lr;
    const char* base = (const char*)slot + row * 128;
    int sw = (row & 7) << 4;
    #pragma unroll
    for (int ks = 0; ks < 2; ++ks)
      af[mi][ks] = *(const i32x4*)(base + ((ks * 64 + lg * 16) ^ sw));
  }
}
__device__ __forceinline__ void rdB(const s8* slot, int wn, int lr, int lg,
                                    i32x4 bf[2][2]) {
  #pragma unroll
  for (int ni = 0; ni < 2; ++ni) {
    int row = wn * 32 + ni * 16 + lr;
    const char* base = (const char*)slot + row * 128;
    int sw = (row & 7) << 4;
    #pragma unroll
    for (int ks = 0; ks < 2; ++ks)
      bf[ni][ks] = *(const i32x4*)(base + ((ks * 64 + lg * 16) ^ sw));
  }
}
template <int PM, int PN>
__device__ __forceinline__ void mfma_phase(i32x4 (&acc)[2][2][4][2],
                                           const i32x4 (&af)[4][2],
                                           const i32x4 (&bf)[2][2]) {
  __builtin_amdgcn_s_setprio(1);
  #pragma unroll
  for (int mi = 0; mi < 4; ++mi)
    #pragma unroll
    for (int ni = 0; ni < 2; ++ni)
      #pragma unroll
      for (int ks = 0; ks < 2; ++ks)
        acc[PM][PN][mi][ni] = mfma_i8(af[mi][ks], bf[ni][ks], acc[PM][PN][mi][ni]);
  __builtin_amdgcn_s_setprio(0);
}

__device__ void gemm256(const s8* __restrict__ A, const s8* __restrict__ Bm,
                        float* __restrict__ C, int Ncols, int m0, int n0,
                        int k0, int nkt, float scale, unsigned* omax, s8* S) {
  const int tid = threadIdx.x;
  const int wave = tid >> 6, lane = tid & 63;
  const int lr = lane & 15, lg = lane >> 4;
  const int wm = wave >> 2, wn = wave & 3;
  s8* SA00 = S;          s8* SA01 = S + 16384;
  s8* SB00 = S + 32768;  s8* SB01 = S + 49152;
  s8* SA10 = S + 65536;  s8* SA11 = S + 81920;
  s8* SB10 = S + 98304;  s8* SB11 = S + 114688;
  // staging: thread t covers rows r0, r0+64 at pre-swizzled byte col ce
  const int r0 = tid >> 3;
  const int ce = ((tid & 7) * 16) ^ ((r0 & 7) << 4);
  const s8* pa0 = A + (size_t)(m0 + r0) * HID + k0 + ce;
  const s8* pa1 = pa0 + (size_t)128 * HID;
  const s8* pb0 = Bm + (size_t)(n0 + r0) * HID + k0 + ce;
  const s8* pb1 = pb0 + (size_t)128 * HID;
  const int wdst = wave * 1024;
  i32x4 acc[2][2][4][2] = {};
  i32x4 af[4][2], bf[2][2];

  auto STG = [&](const s8* p, s8* slot, int tcol) {
    const s8* g = p + tcol * 128;
    gload16(g, slot + wdst);
    gload16(g + (size_t)64 * HID, slot + 8192 + wdst);
  };

  // prologue: tile0 complete + 3 half-tiles of tile1 in flight
  STG(pa0, SA00, 0); STG(pb0, SB00, 0); STG(pa1, SA01, 0); STG(pb1, SB01, 0);
  STG(pa0, SA10, 1); STG(pb1, SB11, 1); STG(pa1, SA11, 1);
  VM6(); PBAR();

  #pragma unroll 1
  for (int t = 0; t < nkt; t += 2) {
    const bool g2 = t + 2 < nkt, g3 = t + 3 < nkt;
    // ph1 (0,0) on tile t (buf0)
    rdA(SA00, wm, lr, lg, af); rdB(SB00, wn, lr, lg, bf);
    STG(pb0, SB10, t + 1);
    PBAR(); mfma_phase<0, 0>(acc, af, bf); PBAR();
    // ph2 (0,1)
    rdB(SB01, wn, lr, lg, bf);
    if (g2) STG(pa0, SA00, t + 2);
    PBAR(); mfma_phase<0, 1>(acc, af, bf); PBAR();
    // ph3 (1,1)
    rdA(SA01, wm, lr, lg, af);
    if (g2) STG(pb1, SB01, t + 2);
    PBAR(); mfma_phase<1, 1>(acc, af, bf); PBAR();
    // ph4 (1,0)
    rdB(SB00, wn, lr, lg, bf);
    if (g2) STG(pa1, SA01, t + 2);
    PBAR(); mfma_phase<1, 0>(acc, af, bf);
    if (g2) { VM6(); } else { VM0(); }  // tail: drain last-tile stages fully
    PBAR();
    // ph5 (0,0) on tile t+1 (buf1)
    rdA(SA10, wm, lr, lg, af); rdB(SB10, wn, lr, lg, bf);
    if (g2) STG(pb0, SB00, t + 2);
    PBAR(); mfma_phase<0, 0>(acc, af, bf); PBAR();
    // ph6 (0,1)
    rdB(SB11, wn, lr, lg, bf);
    if (g3) STG(pa0, SA10, t + 3);
    PBAR(); mfma_phase<0, 1>(acc, af, bf); PBAR();
    // ph7 (1,1)
    rdA(SA11, wm, lr, lg, af);
    if (g3) STG(pb1, SB11, t + 3);
    PBAR(); mfma_phase<1, 1>(acc, af, bf); PBAR();
    // ph8 (1,0)
    rdB(SB10, wn, lr, lg, bf);
    if (g3) STG(pa1, SA11, t + 3);
    PBAR(); mfma_phase<1, 0>(acc, af, bf); VM6(); PBAR();
  }

  float gm = 0.f;
  #pragma unroll
  for (int mh = 0; mh < 2; ++mh)
    #pragma unroll
    for (int nh = 0; nh < 2; ++nh)
      #pragma unroll
      for (int mi = 0; mi < 4; ++mi)
        #pragma unroll
        for (int ni = 0; ni < 2; ++ni) {
          size_t rbase = (size_t)(m0 + mh * 128 + wm * 64 + mi * 16 + lg * 4);
          int cb = n0 + nh * 128 + wn * 32 + ni * 16 + lr;
          #pragma unroll
          for (int r = 0; r < 4; ++r) {
            float v = (float)acc[mh][nh][mi][ni][r] * scale;
            gm = fmaxf(gm, fabsf(v));
            C[(rbase + r) * (size_t)Ncols + cb] = v;
          }
        }
  if (omax) atomic_absmax(omax, gm, lane);
}

// fused Q/K/V projection: 192 blocks (8 M-tiles x 24 N-tiles), XCD-swizzled
__global__ __launch_bounds__(512, 1) void gemm_qkv8(
    const s8* __restrict__ Xq, const s8* __restrict__ Wqb,
    const s8* __restrict__ Wkb, const s8* __restrict__ Wvb,
    float* __restrict__ qf, float* __restrict__ kf, float* __restrict__ vf,
    const unsigned* __restrict__ sc, unsigned* __restrict__ vmax) {
  extern __shared__ __align__(16) s8 S[];
  int raw = blockIdx.x;
  int wg = (raw & 7) * 24 + (raw >> 3);
  int bx = wg & 7, by = wg >> 3;
  const s8* Bm; float* C; int Ncols, n0, sslot; unsigned* om = nullptr;
  if (by < 16)      { Bm = Wqb; C = qf; Ncols = HID;      n0 = by * 256;        sslot = 1; }
  else if (by < 20) { Bm = Wkb; C = kf; Ncols = NKV * HD; n0 = (by - 16) * 256; sslot = 2; }
  else              { Bm = Wvb; C = vf; Ncols = NKV * HD; n0 = (by - 20) * 256; sslot = 3; om = vmax; }
  float scale = get_scale(sc, 0) * get_scale(sc, sslot);
  gemm256(Xq, Bm, C, Ncols, bx * 256, n0, 0, 32, scale, om, S);
}

// O projection, split-K=2: 256 blocks (128 tiles x 2 K-halves), XCD-swizzled
__global__ __launch_bounds__(512, 1) void gemm_o8(
    const s8* __restrict__ A, const s8* __restrict__ Bm,
    float* __restrict__ P0, float* __restrict__ P1,
    const unsigned* __restrict__ sc) {
  extern __shared__ __align__(16) s8 S[];
  int raw = blockIdx.x;
  int wg = (raw & 7) * 32 + (raw >> 3);   // 256 = 8 XCD x 32, bijective
  int tile = wg >> 1, half = wg & 1;
  int by = tile & 15, bx = tile >> 4;
  float scale = get_scale(sc, 8) * get_scale(sc, 4);
  gemm256(A, Bm, half ? P1 : P0, HID, bx * 256, by * 256, half * 2048, 16,
          scale, nullptr, S);
}

// ---------------- RoPE cos/sin table (pos x 64) -----------------------------
__global__ void rope_tab_k(float2* __restrict__ tab) {
  int i = blockIdx.x * 256 + threadIdx.x;  // 65536
  int pos = i >> 6, d = i & 63;
  float inv = exp2f((float)d * (-13.287712379549449f / 64.0f));
  float ang = (float)pos * inv;
  tab[i] = make_float2(cosf(ang), sinf(ang));
}

// ---------------- RoPE in-place + absmax, q & k fused, float4-vectorized ----
__global__ void rope2_k(float* __restrict__ qf, float* __restrict__ kf,
                        unsigned* __restrict__ sc, const float2* __restrict__ tab) {
  int reg = blockIdx.y;
  float* q = reg ? kf : qf;
  int nheads = reg ? NKV : NH;
  unsigned* om = sc + (reg ? 6 : 5);
  int total = B_ * S_ * nheads * 16;  // groups of 4 dims
  int stride = gridDim.x * blockDim.x;
  float m = 0.f;
  for (int i = blockIdx.x * blockDim.x + threadIdx.x; i < total; i += stride) {
    int g = i & 15;
    int h = (i >> 4) % nheads;
    int bs = i / (16 * nheads);
    int pos = bs & (S_ - 1);
    size_t base = ((size_t)bs * nheads + h) * HD + g * 4;
    float4 x1 = *(float4*)(q + base);
    float4 x2 = *(float4*)(q + base + 64);
    const float4* t = (const float4*)(tab + ((size_t)pos << 6) + g * 4);
    float4 t0 = t[0], t1 = t[1];  // {c0,s0,c1,s1}, {c2,s2,c3,s3}
    float4 o1, o2;
    o1.x = x1.x * t0.x - x2.x * t0.y;  o2.x = x2.x * t0.x + x1.x * t0.y;
    o1.y = x1.y * t0.z - x2.y * t0.w;  o2.y = x2.y * t0.z + x1.y * t0.w;
    o1.z = x1.z * t1.x - x2.z * t1.y;  o2.z = x2.z * t1.x + x1.z * t1.y;
    o1.w = x1.w * t1.z - x2.w * t1.w;  o2.w = x2.w * t1.z + x1.w * t1.w;
    *(float4*)(q + base) = o1;
    *(float4*)(q + base + 64) = o2;
    m = fmaxf(m, fmaxf(max4(o1), max4(o2)));
  }
  atomic_absmax(om, m, threadIdx.x & 63);
}

// ---------------- quantize q & k fused (bf16 for attn) ----------------------
__global__ void quantqk_k(const float4* __restrict__ qf, const float4* __restrict__ kf,
                          u16x4* __restrict__ qq, u16x4* __restrict__ kq,
                          const unsigned* __restrict__ sc) {
  int reg = blockIdx.y;
  const float4* x = reg ? kf : qf;
  u16x4* y = reg ? kq : qq;
  int n4 = reg ? (B_ * S_ * NKV * HD / 4) : (B_ * S_ * HID / 4);
  float s = get_scale(sc, reg ? 6 : 5);
  int stride = gridDim.x * blockDim.x;
  for (int i = blockIdx.x * blockDim.x + threadIdx.x; i < n4; i += stride) {
    float4 v = x[i];
    u16x4 o;
    o[0] = f2bf(fminf(fmaxf(rintf(v.x / s), -127.f), 127.f));
    o[1] = f2bf(fminf(fmaxf(rintf(v.y / s), -127.f), 127.f));
    o[2] = f2bf(fminf(fmaxf(rintf(v.z / s), -127.f), 127.f));
    o[3] = f2bf(fminf(fmaxf(rintf(v.w / s), -127.f), 127.f));
    y[i] = o;
  }
}

// ---------------- V: quantize + transpose to (B,NKV,HD,S), LDS-tiled --------
__global__ __launch_bounds__(256) void vquant_t_k(const float* __restrict__ vf,
                                                  unsigned* __restrict__ vtw,
                                                  const unsigned* __restrict__ sc) {
  __shared__ u16 Ls[64 * 132];
  float s = get_scale(sc, 7);
  int st = blockIdx.x & 15, kvh = (blockIdx.x >> 4) & 7, b = blockIdx.x >> 7;
  int s0 = st * 64;
  #pragma unroll
  for (int i = 0; i < 8; ++i) {
    int o = i * 256 + threadIdx.x;
    int sr = o >> 5, c4 = o & 31;
    float4 v = *(const float4*)(vf + ((size_t)(b * S_ + s0 + sr)) * (NKV * HD) +
                                kvh * HD + c4 * 4);
    u16x4 w;
    w[0] = f2bf(fminf(fmaxf(rintf(v.x / s), -127.f), 127.f));
    w[1] = f2bf(fminf(fmaxf(rintf(v.y / s), -127.f), 127.f));
    w[2] = f2bf(fminf(fmaxf(rintf(v.z / s), -127.f), 127.f));
    w[3] = f2bf(fminf(fmaxf(rintf(v.w / s), -127.f), 127.f));
    *(u16x4*)(Ls + sr * 132 + c4 * 4) = w;
  }
  __syncthreads();
  #pragma unroll
  for (int i = 0; i < 16; ++i) {
    int o = i * 256 + threadIdx.x;
    int d = o >> 5, sj = o & 31;
    unsigned lo = Ls[(sj * 2) * 132 + d], hi = Ls[(sj * 2 + 1) * 132 + d];
    vtw[(((size_t)(b * NKV + kvh) * HD + d) << 9) + st * 32 + sj] = lo | (hi << 16);
  }
}

// ---------------- two-pass quantized causal GQA attention (bf16) ------------
__global__ __launch_bounds__(512) void attn_k(
    const u16* __restrict__ Q, const u16* __restrict__ Kq, const u16* __restrict__ Vt,
    float* __restrict__ O, const unsigned* __restrict__ sc, unsigned* __restrict__ omax) {
  __shared__ __align__(16) u16 Ks[2][64 * 128];
  __shared__ __align__(16) u16 Vs[2][128 * 64];
  __shared__ __align__(16) u16 Ps[128 * 64];
  const int tid = threadIdx.x;
  const int wave = tid >> 6, lane = tid & 63;
  const int lr = lane & 15, lg = lane >> 4;
  const int raw = blockIdx.x;
  const int xcd = raw & 7, j = raw >> 3;
  const int grp = xcd + 8 * (j >> 4);
  const int within = j & 15;
  const int b = grp >> 3, kvh = grp & 7;
  const int h = kvh * 4 + (within >> 2);
  const int qp = within & 3;
  const float sq = get_scale(sc, 5), sk = get_scale(sc, 6), sv = get_scale(sc, 7);
  const float c2 = sq * sk * 0.08838834764831845f * LOG2E;
  const float M0 = 32.0f;
  const int k_rin = lane >> 4;
  const int k_cb0 = (lane & 15) * 16;
  const int v_rin = lane >> 3;
  const int v_cb = ((lane & 7) * 16) ^ ((v_rin & 7) << 4);
  float gmax = 0.f;

  auto stageK = [&](int buf, int kt) {
    #pragma unroll
    for (int i = 0; i < 2; ++i) {
      int ch = wave * 2 + i;
      int row = ch * 4 + k_rin;
      int cb = k_cb0 ^ ((row & 7) << 4);
      gload16(Kq + (size_t)(b * S_ + kt * 64 + row) * (NKV * HD) + kvh * HD + (cb >> 1),
              Ks[buf] + ch * 512);
    }
  };
  auto stageV = [&](int buf, int kt) {
    #pragma unroll
    for (int i = 0; i < 2; ++i) {
      int ch = wave * 2 + i;
      int vrow = ch * 8 + v_rin;
      gload16(Vt + ((size_t)(b * NKV + kvh) * HD + vrow) * S_ + kt * 64 + (v_cb >> 1),
              Vs[buf] + ch * 512);
    }
  };

  for (int pi = 0; pi < 2; ++pi) {
    const int qt = pi ? 7 - qp : qp;
    const int q0 = qt * 128;
    const int nkt = 2 * (qt + 1);
    const int qwmin = q0 + wave * 16;
    s16x8 aq[4];
    {
      const u16* qp_ = Q + (size_t)(b * S_ + q0 + wave * 16 + lr) * HID + h * HD + lg * 8;
      #pragma unroll
      for (int ks = 0; ks < 4; ++ks) aq[ks] = *(const s16x8*)(qp_ + ks * 32);
    }
    float ll[4] = {0.f, 0.f, 0.f, 0.f};

    // ---- pass 1: denominator only, fixed reference M0 ----
    stageK(0, 0);
    __syncthreads();
    for (int kt = 0; kt < nkt; ++kt) {
      const int p = kt & 1;
      if (kt < nkt - 1) stageK(p ^ 1, kt + 1);
      f32x4 sacc[4] = {};
      __builtin_amdgcn_s_setprio(1);
      #pragma unroll
      for (int ks = 0; ks < 4; ++ks)
        #pragma unroll
        for (int n = 0; n < 4; ++n) {
          int row = n * 16 + lr;
          s16x8 bk = *(const s16x8*)((const char*)Ks[p] + row * 256 +
                                     ((ks * 64 + lg * 16) ^ ((row & 7) << 4)));
          sacc[n] = mfma16(aq[ks], bk, sacc[n]);
        }
      __builtin_amdgcn_s_setprio(0);
      if (kt * 64 + 63 <= qwmin) {
        #pragma unroll
        for (int r = 0; r < 4; ++r)
          #pragma unroll
          for (int n = 0; n < 4; ++n)
            ll[r] += exp2f(fmaf(sacc[n][r], c2, -M0));
      } else {
        #pragma unroll
        for (int r = 0; r < 4; ++r) {
          int qg = qwmin + lg * 4 + r;
          #pragma unroll
          for (int n = 0; n < 4; ++n) {
            int kg = kt * 64 + n * 16 + lr;
            float e = exp2f(fmaf(sacc[n][r], c2, -M0));
            ll[r] += (kg <= qg) ? e : 0.f;
          }
        }
      }
      __syncthreads();
    }
    float bias[4];
    #pragma unroll
    for (int r = 0; r < 4; ++r) {
      float l = ll[r];
      #pragma unroll
      for (int o = 8; o >= 1; o >>= 1) l += __shfl_xor(l, o);
      bias[r] = 6.9886846867721655f - __log2f(l) - M0;  // log2(127) - log2(l) - M0
    }

    // ---- pass 2: recompute S, quantize P, PV ----
    f32x4 oacc[8] = {};
    stageK(0, 0); stageV(0, 0);
    __syncthreads();
    for (int kt = 0; kt < nkt; ++kt) {
      const int p = kt & 1;
      if (kt < nkt - 1) { stageK(p ^ 1, kt + 1); stageV(p ^ 1, kt + 1); }
      f32x4 sacc[4] = {};
      __builtin_amdgcn_s_setprio(1);
      #pragma unroll
      for (int ks = 0; ks < 4; ++ks)
        #pragma unroll
        for (int n = 0; n < 4; ++n) {
          int row = n * 16 + lr;
          s16x8 bk = *(const s16x8*)((const char*)Ks[p] + row * 256 +
                                     ((ks * 64 + lg * 16) ^ ((row & 7) << 4)));
          sacc[n] = mfma16(aq[ks], bk, sacc[n]);
        }
      __builtin_amdgcn_s_setprio(0);
      if (kt * 64 + 63 <= qwmin) {
        #pragma unroll
        for (int r = 0; r < 4; ++r) {
          int prow = wave * 16 + lg * 4 + r;
          #pragma unroll
          for (int n = 0; n < 4; ++n) {
            float p127 = rintf(exp2f(fmaf(sacc[n][r], c2, bias[r])));
            int col = n * 16 + lr;
            *(u16*)((char*)Ps + prow * 128 + ((col * 2) ^ ((prow & 7) << 4))) = f2bf(p127);
          }
        }
      } else {
        #pragma unroll
        for (int r = 0; r < 4; ++r) {
          int prow = wave * 16 + lg * 4 + r;
          int qg = qwmin + lg * 4 + r;
          #pragma unroll
          for (int n = 0; n < 4; ++n) {
            int kg = kt * 64 + n * 16 + lr;
            float a = fmaf(sacc[n][r], c2, bias[r]);
            float p127 = (kg <= qg) ? rintf(exp2f(a)) : 0.f;
            int col = n * 16 + lr;
            *(u16*)((char*)Ps + prow * 128 + ((col * 2) ^ ((prow & 7) << 4))) = f2bf(p127);
          }
        }
      }
      __builtin_amdgcn_s_setprio(1);
      #pragma unroll
      for (int ks = 0; ks < 2; ++ks) {
        int prow = wave * 16 + lr;
        s16x8 ap = *(const s16x8*)((const char*)Ps + prow * 128 +
                                   ((ks * 64 + lg * 16) ^ ((prow & 7) << 4)));
        #pragma unroll
        for (int n = 0; n < 8; ++n) {
          int vrow = n * 16 + lr;
          s16x8 bv = *(const s16x8*)((const char*)Vs[p] + vrow * 128 +
                                     ((ks * 64 + lg * 16) ^ ((vrow & 7) << 4)));
          oacc[n] = mfma16(ap, bv, oacc[n]);
        }
      }
      __builtin_amdgcn_s_setprio(0);
      __syncthreads();
    }
    const float pvs = sv * (1.0f / 127.0f);
    #pragma unroll
    for (int n = 0; n < 8; ++n)
      #pragma unroll
      for (int r = 0; r < 4; ++r) {
        float v = oacc[n][r] * pvs;
        gmax = fmaxf(gmax, fabsf(v));
        O[(size_t)(b * S_ + q0 + wave * 16 + lg * 4 + r) * HID + h * HD + n * 16 + lr] = v;
      }
  }
  atomic_absmax(omax, gmax, lane);
}

// ---------------------------------------------------------------------------
extern "C" void kernel_launch(void* const* d_in, const int* in_sizes, int n_in,
                              void* d_out, int out_size, void* d_ws, size_t ws_size,
                              hipStream_t stream) {
  const float* hs = (const float*)d_in[0];
  const float* Wq = (const float*)d_in[3];
  const float* Wk = (const float*)d_in[4];
  const float* Wv = (const float*)d_in[5];
  const float* Wo = (const float*)d_in[6];
  float* out = (float*)d_out;
  char* ws = (char*)d_ws;

  unsigned* sc = (unsigned*)ws;  // 0=x 1=Wq 2=Wk 3=Wv 4=Wo 5=q 6=k 7=v 8=attn_out
  size_t off = 256;
  s8* Xq = (s8*)(ws + off); off += (size_t)B_ * S_ * HID;          // 8MB
  size_t wqb_off = off;
  s8* Wqb = (s8*)(ws + off); off += (size_t)HID * HID;             // 16MB
  s8* Wkb = (s8*)(ws + off); off += (size_t)NKV * HD * HID;        // 4MB
  s8* Wvb = (s8*)(ws + off); off += (size_t)NKV * HD * HID;        // 4MB
  s8* Wob = (s8*)(ws + off); off += (size_t)HID * HID;             // 16MB
  size_t qf_off = off;
  float* qf = (float*)(ws + off); off += (size_t)B_ * S_ * HID * 4;       // 32MB
  size_t kf_off = off;
  float* kf = (float*)(ws + off); off += (size_t)B_ * S_ * NKV * HD * 4;  // 8MB
  float* vf = (float*)(ws + off); off += (size_t)B_ * S_ * NKV * HD * 4;  // 8MB
  u16* qq = (u16*)(ws + off); off += (size_t)B_ * S_ * HID * 2;           // 16MB
  u16* kq = (u16*)(ws + off); off += (size_t)B_ * S_ * NKV * HD * 2;      // 4MB
  u16* vt = (u16*)(ws + off); off += (size_t)B_ * S_ * NKV * HD * 2;      // 4MB
  float2* tab = (float2*)(ws + off); off += (size_t)S_ * 64 * 8;
  float* attnf = (float*)(ws + qf_off);  // alias qf (dead after quantqk)
  s8* attnq = (s8*)(ws + wqb_off);       // alias Wqb (dead after gemm_qkv8)
  // split-K partials for O-proj: both regions dead by the time gemm_o8 runs
  // (attnf consumed by quant_k; kf..vt consumed by attn_k). 32MB each.
  float* P0 = (float*)(ws + qf_off);
  float* P1 = (float*)(ws + kf_off);  // kf+vf+qq+kq+vt span = 40MB >= 32MB

  hipFuncSetAttribute((const void*)gemm_qkv8,
                      hipFuncAttributeMaxDynamicSharedMemorySize, 131072);
  hipFuncSetAttribute((const void*)gemm_o8,
                      hipFuncAttributeMaxDynamicSharedMemorySize, 131072);

  hipMemsetAsync(sc, 0, 64, stream);

  dim3 blk(256);
  absmax5_k<<<2048, blk, 0, stream>>>(
      (const float4*)hs, (const float4*)Wq, (const float4*)Wk,
      (const float4*)Wv, (const float4*)Wo, sc);
  quant5_k<<<2048, blk, 0, stream>>>(
      (const float4*)hs, (const float4*)Wq, (const float4*)Wk,
      (const float4*)Wv, (const float4*)Wo,
      (unsigned*)Xq, (unsigned*)Wqb, (unsigned*)Wkb, (unsigned*)Wvb,
      (unsigned*)Wob, sc);
  rope_tab_k<<<256, blk, 0, stream>>>(tab);

  gemm_qkv8<<<192, 512, 131072, stream>>>(Xq, Wqb, Wkb, Wvb, qf, kf, vf, sc, sc + 7);

  rope2_k<<<dim3(512, 2), blk, 0, stream>>>(qf, kf, sc, tab);
  quantqk_k<<<dim3(512, 2), blk, 0, stream>>>((const float4*)qf, (const float4*)kf,
                                              (u16x4*)qq, (u16x4*)kq, sc);
  vquant_t_k<<<256, blk, 0, stream>>>(vf, (unsigned*)vt, sc);

  attn_k<<<256, 512, 0, stream>>>(qq, kq, vt, attnf, sc, sc + 8);

  quant_k<<<2048, blk, 0, stream>>>((const float4*)attnf, (unsigned*)attnq,
                                    B_ * S_ * HID / 4, sc, 8);
  gemm_o8<<<256, 512, 131072, stream>>>(attnq, Wob, P0, P1, sc);
  add_k<<<2048, blk, 0, stream>>>((const float4*)P0, (const float4*)P1,
                                  (float4*)out, B_ * S_ * HID / 4);
}

// Round 13
// 449.946 us; speedup vs baseline: 1.2401x; 1.0220x over previous
//
#include <hip/hip_runtime.h>
#include <math.h>

#define B_ 2
#define S_ 1024
#define HID 4096
#define NH 32
#define NKV 8
#define HD 128
#define LOG2E 1.44269504088896340736f

typedef short s16x8 __attribute__((ext_vector_type(8)));   // 8 bf16 (4 VGPRs)
typedef float f32x4 __attribute__((ext_vector_type(4)));
typedef int i32x4 __attribute__((ext_vector_type(4)));     // 16B / int32 acc
typedef unsigned short u16;
typedef u16 u16x4 __attribute__((ext_vector_type(4)));
typedef signed char s8;

__device__ __forceinline__ f32x4 mfma16(s16x8 a, s16x8 b, f32x4 c) {
  return __builtin_amdgcn_mfma_f32_16x16x32_bf16(a, b, c, 0, 0, 0);
}
__device__ __forceinline__ i32x4 mfma_i8(i32x4 a, i32x4 b, i32x4 c) {
  return __builtin_amdgcn_mfma_i32_16x16x64_i8(a, b, c, 0, 0, 0);
}
// exact for integer-valued floats |v| <= 127
__device__ __forceinline__ u16 f2bf(float f) {
  union { float f; unsigned u; } v; v.f = f;
  return (u16)(v.u >> 16);
}
__device__ __forceinline__ float get_scale(const unsigned* sc, int slot) {
  return fmaxf(__uint_as_float(sc[slot]) / 127.0f, 1e-8f);
}
__device__ __forceinline__ int q127(float x, float s) {
  return (int)fminf(fmaxf(rintf(x / s), -127.f), 127.f);
}
__device__ __forceinline__ unsigned pack4(float4 v, float s) {
  return (q127(v.x, s) & 255) | ((q127(v.y, s) & 255) << 8) |
         ((q127(v.z, s) & 255) << 16) | ((q127(v.w, s) & 255) << 24);
}
__device__ __forceinline__ float max4(float4 v) {
  return fmaxf(fmaxf(fabsf(v.x), fabsf(v.y)), fmaxf(fabsf(v.z), fabsf(v.w)));
}
__device__ __forceinline__ void gload16(const void* g, void* l) {
  __builtin_amdgcn_global_load_lds(
      (const __attribute__((address_space(1))) unsigned*)g,
      (__attribute__((address_space(3))) unsigned*)l, 16, 0, 0);
}
__device__ __forceinline__ void atomic_absmax(unsigned* out, float m, int lane) {
  #pragma unroll
  for (int o = 32; o >= 1; o >>= 1) m = fmaxf(m, __shfl_xor(m, o));
  if (lane == 0) atomicMax(out, __float_as_uint(m));
}

#define SB_() __builtin_amdgcn_sched_barrier(0)
#define PBAR() do { SB_(); __builtin_amdgcn_s_barrier(); SB_(); } while (0)
#define VM6() do { SB_(); asm volatile("s_waitcnt vmcnt(6)" ::: "memory"); } while (0)
#define VM0() do { SB_(); asm volatile("s_waitcnt vmcnt(0)" ::: "memory"); } while (0)

// work-proportional block partition for the 5 input tensors (2:4:1:1:4 /12)
__device__ __forceinline__ void tensor_pick(int blk, int& r, int& b0, int& nb) {
  if (blk < 342)       { r = 0; b0 = 0;    nb = 342; }
  else if (blk < 1024) { r = 1; b0 = 342;  nb = 682; }
  else if (blk < 1195) { r = 2; b0 = 1024; nb = 171; }
  else if (blk < 1366) { r = 3; b0 = 1195; nb = 171; }
  else                 { r = 4; b0 = 1366; nb = 682; }
}

// ---------------- fused absmax over the 5 input tensors ---------------------
__global__ void absmax5_k(const float4* __restrict__ p0, const float4* __restrict__ p1,
                          const float4* __restrict__ p2, const float4* __restrict__ p3,
                          const float4* __restrict__ p4, unsigned* __restrict__ sc) {
  int r, b0, nb;
  tensor_pick(blockIdx.x, r, b0, nb);
  const float4* x; int n4;
  if (r == 0)      { x = p0; n4 = B_ * S_ * HID / 4; }
  else if (r == 1) { x = p1; n4 = HID * HID / 4; }
  else if (r == 2) { x = p2; n4 = NKV * HD * HID / 4; }
  else if (r == 3) { x = p3; n4 = NKV * HD * HID / 4; }
  else             { x = p4; n4 = HID * HID / 4; }
  const int stride = nb * 256;
  int i = (blockIdx.x - b0) * 256 + threadIdx.x;
  float m0 = 0.f, m1 = 0.f, m2 = 0.f, m3 = 0.f;
  for (; i + 3 * stride < n4; i += 4 * stride) {
    float4 v0 = x[i], v1 = x[i + stride], v2 = x[i + 2 * stride], v3 = x[i + 3 * stride];
    m0 = fmaxf(m0, max4(v0)); m1 = fmaxf(m1, max4(v1));
    m2 = fmaxf(m2, max4(v2)); m3 = fmaxf(m3, max4(v3));
  }
  for (; i < n4; i += stride) m0 = fmaxf(m0, max4(x[i]));
  float m = fmaxf(fmaxf(m0, m1), fmaxf(m2, m3));
  atomic_absmax(sc + r, m, threadIdx.x & 63);
}

// ---------------- fused quantize of the 5 input tensors -> s8 ---------------
__global__ void quant5_k(const float4* __restrict__ p0, const float4* __restrict__ p1,
                         const float4* __restrict__ p2, const float4* __restrict__ p3,
                         const float4* __restrict__ p4,
                         unsigned* __restrict__ y0, unsigned* __restrict__ y1,
                         unsigned* __restrict__ y2, unsigned* __restrict__ y3,
                         unsigned* __restrict__ y4, const unsigned* __restrict__ sc) {
  int r, b0, nb;
  tensor_pick(blockIdx.x, r, b0, nb);
  const float4* x; unsigned* y; int n4;
  if (r == 0)      { x = p0; y = y0; n4 = B_ * S_ * HID / 4; }
  else if (r == 1) { x = p1; y = y1; n4 = HID * HID / 4; }
  else if (r == 2) { x = p2; y = y2; n4 = NKV * HD * HID / 4; }
  else if (r == 3) { x = p3; y = y3; n4 = NKV * HD * HID / 4; }
  else             { x = p4; y = y4; n4 = HID * HID / 4; }
  float s = get_scale(sc, r);
  const int stride = nb * 256;
  int i = (blockIdx.x - b0) * 256 + threadIdx.x;
  for (; i + 3 * stride < n4; i += 4 * stride) {
    float4 v0 = x[i], v1 = x[i + stride], v2 = x[i + 2 * stride], v3 = x[i + 3 * stride];
    y[i] = pack4(v0, s);
    y[i + stride] = pack4(v1, s);
    y[i + 2 * stride] = pack4(v2, s);
    y[i + 3 * stride] = pack4(v3, s);
  }
  for (; i < n4; i += stride) y[i] = pack4(x[i], s);
}

// ---------------- generic quantize (attn output) -> s8 ----------------------
__global__ void quant_k(const float4* __restrict__ x, unsigned* __restrict__ y, int n4,
                        const unsigned* __restrict__ sc, int slot) {
  float s = get_scale(sc, slot);
  int stride = gridDim.x * blockDim.x;
  int i = blockIdx.x * blockDim.x + threadIdx.x;
  for (; i + 3 * stride < n4; i += 4 * stride) {
    float4 v0 = x[i], v1 = x[i + stride], v2 = x[i + 2 * stride], v3 = x[i + 3 * stride];
    y[i] = pack4(v0, s);
    y[i + stride] = pack4(v1, s);
    y[i + 2 * stride] = pack4(v2, s);
    y[i + 3 * stride] = pack4(v3, s);
  }
  for (; i < n4; i += stride) y[i] = pack4(x[i], s);
}

// ---------------- split-K reduce: out = P0 + P1 -----------------------------
__global__ void add_k(const float4* __restrict__ p0, const float4* __restrict__ p1,
                      float4* __restrict__ out, int n4) {
  int stride = gridDim.x * blockDim.x;
  int i = blockIdx.x * blockDim.x + threadIdx.x;
  for (; i + stride < n4; i += 2 * stride) {
    float4 a0 = p0[i], b0 = p1[i], a1 = p0[i + stride], b1 = p1[i + stride];
    out[i] = make_float4(a0.x + b0.x, a0.y + b0.y, a0.z + b0.z, a0.w + b0.w);
    out[i + stride] = make_float4(a1.x + b1.x, a1.y + b1.y, a1.z + b1.z, a1.w + b1.w);
  }
  for (; i < n4; i += stride) {
    float4 a = p0[i], b = p1[i];
    out[i] = make_float4(a.x + b.x, a.y + b.y, a.z + b.z, a.w + b.w);
  }
}

// ============ 256x256 8-phase int8 GEMM (T2+T3+T4+T5) ========================
__device__ __forceinline__ void rdA(const s8* slot, int wm, int lr, int lg,
                                    i32x4 af[4][2]) {
  #pragma unroll
  for (int mi = 0; mi < 4; ++mi) {
    int row = wm * 64 + mi * 16 + lr;
    const char* base = (const char*)slot + row * 128;
    int sw = (row & 7) << 4;
    #pragma unroll
    for (int ks = 0; ks < 2; ++ks)
      af[mi][ks] = *(const i32x4*)(base + ((ks * 64 + lg * 16) ^ sw));
  }
}
__device__ __forceinline__ void rdB(const s8* slot, int wn, int lr, int lg,
                                    i32x4 bf[2][2]) {
  #pragma unroll
  for (int ni = 0; ni < 2; ++ni) {
    int row = wn * 32 + ni * 16 + lr;
    const char* base = (const char*)slot + row * 128;
    int sw = (row & 7) << 4;
    #pragma unroll
    for (int ks = 0; ks < 2; ++ks)
      bf[ni][ks] = *(const i32x4*)(base + ((ks * 64 + lg * 16) ^ sw));
  }
}
template <int PM, int PN>
__device__ __forceinline__ void mfma_phase(i32x4 (&acc)[2][2][4][2],
                                           const i32x4 (&af)[4][2],
                                           const i32x4 (&bf)[2][2]) {
  __builtin_amdgcn_s_setprio(1);
  #pragma unroll
  for (int mi = 0; mi < 4; ++mi)
    #pragma unroll
    for (int ni = 0; ni < 2; ++ni)
      #pragma unroll
      for (int ks = 0; ks < 2; ++ks)
        acc[PM][PN][mi][ni] = mfma_i8(af[mi][ks], bf[ni][ks], acc[PM][PN][mi][ni]);
  __builtin_amdgcn_s_setprio(0);
}

__device__ void gemm256(const s8* __restrict__ A, const s8* __restrict__ Bm,
                        float* __restrict__ C, int Ncols, int m0, int n0,
                        int k0, int nkt, float scale, unsigned* omax, s8* S) {
  const int tid = threadIdx.x;
  const int wave = tid >> 6, lane = tid & 63;
  const int lr = lane & 15, lg = lane >> 4;
  const int wm = wave >> 2, wn = wave & 3;
  s8* SA00 = S;          s8* SA01 = S + 16384;
  s8* SB00 = S + 32768;  s8* SB01 = S + 49152;
  s8* SA10 = S + 65536;  s8* SA11 = S + 81920;
  s8* SB10 = S + 98304;  s8* SB11 = S + 114688;
  const int r0 = tid >> 3;
  const int ce = ((tid & 7) * 16) ^ ((r0 & 7) << 4);
  const s8* pa0 = A + (size_t)(m0 + r0) * HID + k0 + ce;
  const s8* pa1 = pa0 + (size_t)128 * HID;
  const s8* pb0 = Bm + (size_t)(n0 + r0) * HID + k0 + ce;
  const s8* pb1 = pb0 + (size_t)128 * HID;
  const int wdst = wave * 1024;
  i32x4 acc[2][2][4][2] = {};
  i32x4 af[4][2], bf[2][2];

  auto STG = [&](const s8* p, s8* slot, int tcol) {
    const s8* g = p + tcol * 128;
    gload16(g, slot + wdst);
    gload16(g + (size_t)64 * HID, slot + 8192 + wdst);
  };

  STG(pa0, SA00, 0); STG(pb0, SB00, 0); STG(pa1, SA01, 0); STG(pb1, SB01, 0);
  STG(pa0, SA10, 1); STG(pb1, SB11, 1); STG(pa1, SA11, 1);
  VM6(); PBAR();

  #pragma unroll 1
  for (int t = 0; t < nkt; t += 2) {
    const bool g2 = t + 2 < nkt, g3 = t + 3 < nkt;
    rdA(SA00, wm, lr, lg, af); rdB(SB00, wn, lr, lg, bf);
    STG(pb0, SB10, t + 1);
    PBAR(); mfma_phase<0, 0>(acc, af, bf); PBAR();
    rdB(SB01, wn, lr, lg, bf);
    if (g2) STG(pa0, SA00, t + 2);
    PBAR(); mfma_phase<0, 1>(acc, af, bf); PBAR();
    rdA(SA01, wm, lr, lg, af);
    if (g2) STG(pb1, SB01, t + 2);
    PBAR(); mfma_phase<1, 1>(acc, af, bf); PBAR();
    rdB(SB00, wn, lr, lg, bf);
    if (g2) STG(pa1, SA01, t + 2);
    PBAR(); mfma_phase<1, 0>(acc, af, bf);
    if (g2) { VM6(); } else { VM0(); }
    PBAR();
    rdA(SA10, wm, lr, lg, af); rdB(SB10, wn, lr, lg, bf);
    if (g2) STG(pb0, SB00, t + 2);
    PBAR(); mfma_phase<0, 0>(acc, af, bf); PBAR();
    rdB(SB11, wn, lr, lg, bf);
    if (g3) STG(pa0, SA10, t + 3);
    PBAR(); mfma_phase<0, 1>(acc, af, bf); PBAR();
    rdA(SA11, wm, lr, lg, af);
    if (g3) STG(pb1, SB11, t + 3);
    PBAR(); mfma_phase<1, 1>(acc, af, bf); PBAR();
    rdB(SB10, wn, lr, lg, bf);
    if (g3) STG(pa1, SA11, t + 3);
    PBAR(); mfma_phase<1, 0>(acc, af, bf); VM6(); PBAR();
  }

  float gm = 0.f;
  #pragma unroll
  for (int mh = 0; mh < 2; ++mh)
    #pragma unroll
    for (int nh = 0; nh < 2; ++nh)
      #pragma unroll
      for (int mi = 0; mi < 4; ++mi)
        #pragma unroll
        for (int ni = 0; ni < 2; ++ni) {
          size_t rbase = (size_t)(m0 + mh * 128 + wm * 64 + mi * 16 + lg * 4);
          int cb = n0 + nh * 128 + wn * 32 + ni * 16 + lr;
          #pragma unroll
          for (int r = 0; r < 4; ++r) {
            float v = (float)acc[mh][nh][mi][ni][r] * scale;
            gm = fmaxf(gm, fabsf(v));
            C[(rbase + r) * (size_t)Ncols + cb] = v;
          }
        }
  if (omax) atomic_absmax(omax, gm, lane);
}

// fused Q/K/V projection: 192 blocks, XCD-swizzled
__global__ __launch_bounds__(512, 1) void gemm_qkv8(
    const s8* __restrict__ Xq, const s8* __restrict__ Wqb,
    const s8* __restrict__ Wkb, const s8* __restrict__ Wvb,
    float* __restrict__ qf, float* __restrict__ kf, float* __restrict__ vf,
    const unsigned* __restrict__ sc, unsigned* __restrict__ vmax) {
  extern __shared__ __align__(16) s8 S[];
  int raw = blockIdx.x;
  int wg = (raw & 7) * 24 + (raw >> 3);
  int bx = wg & 7, by = wg >> 3;
  const s8* Bm; float* C; int Ncols, n0, sslot; unsigned* om = nullptr;
  if (by < 16)      { Bm = Wqb; C = qf; Ncols = HID;      n0 = by * 256;        sslot = 1; }
  else if (by < 20) { Bm = Wkb; C = kf; Ncols = NKV * HD; n0 = (by - 16) * 256; sslot = 2; }
  else              { Bm = Wvb; C = vf; Ncols = NKV * HD; n0 = (by - 20) * 256; sslot = 3; om = vmax; }
  float scale = get_scale(sc, 0) * get_scale(sc, sslot);
  gemm256(Xq, Bm, C, Ncols, bx * 256, n0, 0, 32, scale, om, S);
}

// O projection, split-K=2: 256 blocks, XCD-swizzled
__global__ __launch_bounds__(512, 1) void gemm_o8(
    const s8* __restrict__ A, const s8* __restrict__ Bm,
    float* __restrict__ P0, float* __restrict__ P1,
    const unsigned* __restrict__ sc) {
  extern __shared__ __align__(16) s8 S[];
  int raw = blockIdx.x;
  int wg = (raw & 7) * 32 + (raw >> 3);
  int tile = wg >> 1, half = wg & 1;
  int by = tile & 15, bx = tile >> 4;
  float scale = get_scale(sc, 8) * get_scale(sc, 4);
  gemm256(A, Bm, half ? P1 : P0, HID, bx * 256, by * 256, half * 2048, 16,
          scale, nullptr, S);
}

// ---------------- RoPE cos/sin table (pos x 64) -----------------------------
__global__ void rope_tab_k(float2* __restrict__ tab) {
  int i = blockIdx.x * 256 + threadIdx.x;  // 65536
  int pos = i >> 6, d = i & 63;
  float inv = exp2f((float)d * (-13.287712379549449f / 64.0f));
  float ang = (float)pos * inv;
  tab[i] = make_float2(cosf(ang), sinf(ang));
}

// ---------------- RoPE in-place + absmax, q & k fused, float4-vectorized ----
__global__ void rope2_k(float* __restrict__ qf, float* __restrict__ kf,
                        unsigned* __restrict__ sc, const float2* __restrict__ tab) {
  int reg = blockIdx.y;
  float* q = reg ? kf : qf;
  int nheads = reg ? NKV : NH;
  unsigned* om = sc + (reg ? 6 : 5);
  int total = B_ * S_ * nheads * 16;
  int stride = gridDim.x * blockDim.x;
  float m = 0.f;
  for (int i = blockIdx.x * blockDim.x + threadIdx.x; i < total; i += stride) {
    int g = i & 15;
    int h = (i >> 4) % nheads;
    int bs = i / (16 * nheads);
    int pos = bs & (S_ - 1);
    size_t base = ((size_t)bs * nheads + h) * HD + g * 4;
    float4 x1 = *(float4*)(q + base);
    float4 x2 = *(float4*)(q + base + 64);
    const float4* t = (const float4*)(tab + ((size_t)pos << 6) + g * 4);
    float4 t0 = t[0], t1 = t[1];
    float4 o1, o2;
    o1.x = x1.x * t0.x - x2.x * t0.y;  o2.x = x2.x * t0.x + x1.x * t0.y;
    o1.y = x1.y * t0.z - x2.y * t0.w;  o2.y = x2.y * t0.z + x1.y * t0.w;
    o1.z = x1.z * t1.x - x2.z * t1.y;  o2.z = x2.z * t1.x + x1.z * t1.y;
    o1.w = x1.w * t1.z - x2.w * t1.w;  o2.w = x2.w * t1.z + x1.w * t1.w;
    *(float4*)(q + base) = o1;
    *(float4*)(q + base + 64) = o2;
    m = fmaxf(m, fmaxf(max4(o1), max4(o2)));
  }
  atomic_absmax(om, m, threadIdx.x & 63);
}

// ---------------- quantize q & k fused -> s8 (for i8 QK^T) ------------------
__global__ void quantqk_k(const float4* __restrict__ qf, const float4* __restrict__ kf,
                          unsigned* __restrict__ qq, unsigned* __restrict__ kq,
                          const unsigned* __restrict__ sc) {
  int reg = blockIdx.y;
  const float4* x = reg ? kf : qf;
  unsigned* y = reg ? kq : qq;
  int n4 = reg ? (B_ * S_ * NKV * HD / 4) : (B_ * S_ * HID / 4);
  float s = get_scale(sc, reg ? 6 : 5);
  int stride = gridDim.x * blockDim.x;
  int i = blockIdx.x * blockDim.x + threadIdx.x;
  for (; i + stride < n4; i += 2 * stride) {
    float4 v0 = x[i], v1 = x[i + stride];
    y[i] = pack4(v0, s);
    y[i + stride] = pack4(v1, s);
  }
  for (; i < n4; i += stride) y[i] = pack4(x[i], s);
}

// ---------------- V: quantize + transpose to (B,NKV,HD,S), bf16 -------------
__global__ __launch_bounds__(256) void vquant_t_k(const float* __restrict__ vf,
                                                  unsigned* __restrict__ vtw,
                                                  const unsigned* __restrict__ sc) {
  __shared__ u16 Ls[64 * 132];
  float s = get_scale(sc, 7);
  int st = blockIdx.x & 15, kvh = (blockIdx.x >> 4) & 7, b = blockIdx.x >> 7;
  int s0 = st * 64;
  #pragma unroll
  for (int i = 0; i < 8; ++i) {
    int o = i * 256 + threadIdx.x;
    int sr = o >> 5, c4 = o & 31;
    float4 v = *(const float4*)(vf + ((size_t)(b * S_ + s0 + sr)) * (NKV * HD) +
                                kvh * HD + c4 * 4);
    u16x4 w;
    w[0] = f2bf(fminf(fmaxf(rintf(v.x / s), -127.f), 127.f));
    w[1] = f2bf(fminf(fmaxf(rintf(v.y / s), -127.f), 127.f));
    w[2] = f2bf(fminf(fmaxf(rintf(v.z / s), -127.f), 127.f));
    w[3] = f2bf(fminf(fmaxf(rintf(v.w / s), -127.f), 127.f));
    *(u16x4*)(Ls + sr * 132 + c4 * 4) = w;
  }
  __syncthreads();
  #pragma unroll
  for (int i = 0; i < 16; ++i) {
    int o = i * 256 + threadIdx.x;
    int d = o >> 5, sj = o & 31;
    unsigned lo = Ls[(sj * 2) * 132 + d], hi = Ls[(sj * 2 + 1) * 132 + d];
    vtw[(((size_t)(b * NKV + kvh) * HD + d) << 9) + st * 32 + sj] = lo | (hi << 16);
  }
}

// ---------------- two-pass quantized causal GQA attention -------------------
// QK^T in int8 MFMA (exact int32 scores), PV in bf16 (unchanged, verified).
// QBLK=128, 8 waves; K tile 64x128 BYTES (8KB) in LDS with ((row&7)<<4)
// swizzle, one gload16/thread; Q fragments 2x i32x4 per lane.  Fixed softmax
// reference M0; causal mask only on non-interior tiles; depth-1 async dbuf;
// Ps wave-private.
__global__ __launch_bounds__(512) void attn_k(
    const s8* __restrict__ Q, const s8* __restrict__ Kq, const u16* __restrict__ Vt,
    float* __restrict__ O, const unsigned* __restrict__ sc, unsigned* __restrict__ omax) {
  __shared__ __align__(16) s8 Ks[2][64 * 128];     // 2 x 8KB
  __shared__ __align__(16) u16 Vs[2][128 * 64];    // 2 x 16KB
  __shared__ __align__(16) u16 Ps[128 * 64];       // 16KB, wave-private rows
  const int tid = threadIdx.x;
  const int wave = tid >> 6, lane = tid & 63;
  const int lr = lane & 15, lg = lane >> 4;
  const int raw = blockIdx.x;
  const int xcd = raw & 7, j = raw >> 3;
  const int grp = xcd + 8 * (j >> 4);
  const int within = j & 15;
  const int b = grp >> 3, kvh = grp & 7;
  const int h = kvh * 4 + (within >> 2);
  const int qp = within & 3;
  const float sq = get_scale(sc, 5), sk = get_scale(sc, 6), sv = get_scale(sc, 7);
  const float c2 = sq * sk * 0.08838834764831845f * LOG2E;
  const float M0 = 32.0f;
  // K staging: 64 rows x 128B, thread t -> row t>>3, pre-swizzled 16B col
  const int k_row = tid >> 3;
  const int k_cb = ((tid & 7) * 16) ^ ((k_row & 7) << 4);
  const int v_rin = lane >> 3;
  const int v_cb = ((lane & 7) * 16) ^ ((v_rin & 7) << 4);
  float gmax = 0.f;

  auto stageK = [&](int buf, int kt) {
    gload16(Kq + (size_t)(b * S_ + kt * 64 + k_row) * (NKV * HD) + kvh * HD + k_cb,
            Ks[buf] + wave * 1024);
  };
  auto stageV = [&](int buf, int kt) {
    #pragma unroll
    for (int i = 0; i < 2; ++i) {
      int ch = wave * 2 + i;
      int vrow = ch * 8 + v_rin;
      gload16(Vt + ((size_t)(b * NKV + kvh) * HD + vrow) * S_ + kt * 64 + (v_cb >> 1),
              Vs[buf] + ch * 512);
    }
  };

  for (int pi = 0; pi < 2; ++pi) {
    const int qt = pi ? 7 - qp : qp;
    const int q0 = qt * 128;
    const int nkt = 2 * (qt + 1);
    const int qwmin = q0 + wave * 16;
    i32x4 aq[2];
    {
      const s8* qp_ = Q + (size_t)(b * S_ + q0 + wave * 16 + lr) * HID + h * HD + lg * 16;
      aq[0] = *(const i32x4*)(qp_);
      aq[1] = *(const i32x4*)(qp_ + 64);
    }
    float ll[4] = {0.f, 0.f, 0.f, 0.f};

    // ---- pass 1: denominator only, fixed reference M0 ----
    stageK(0, 0);
    __syncthreads();
    for (int kt = 0; kt < nkt; ++kt) {
      const int p = kt & 1;
      if (kt < nkt - 1) stageK(p ^ 1, kt + 1);
      i32x4 sacc[4] = {};
      __builtin_amdgcn_s_setprio(1);
      #pragma unroll
      for (int ks = 0; ks < 2; ++ks)
        #pragma unroll
        for (int n = 0; n < 4; ++n) {
          int row = n * 16 + lr;
          i32x4 bk = *(const i32x4*)((const char*)Ks[p] + row * 128 +
                                     ((ks * 64 + lg * 16) ^ ((row & 7) << 4)));
          sacc[n] = mfma_i8(aq[ks], bk, sacc[n]);
        }
      __builtin_amdgcn_s_setprio(0);
      if (kt * 64 + 63 <= qwmin) {
        #pragma unroll
        for (int r = 0; r < 4; ++r)
          #pragma unroll
          for (int n = 0; n < 4; ++n)
            ll[r] += exp2f(fmaf((float)sacc[n][r], c2, -M0));
      } else {
        #pragma unroll
        for (int r = 0; r < 4; ++r) {
          int qg = qwmin + lg * 4 + r;
          #pragma unroll
          for (int n = 0; n < 4; ++n) {
            int kg = kt * 64 + n * 16 + lr;
            float e = exp2f(fmaf((float)sacc[n][r], c2, -M0));
            ll[r] += (kg <= qg) ? e : 0.f;
          }
        }
      }
      __syncthreads();
    }
    float bias[4];
    #pragma unroll
    for (int r = 0; r < 4; ++r) {
      float l = ll[r];
      #pragma unroll
      for (int o = 8; o >= 1; o >>= 1) l += __shfl_xor(l, o);
      bias[r] = 6.9886846867721655f - __log2f(l) - M0;  // log2(127) - log2(l) - M0
    }

    // ---- pass 2: recompute S, quantize P, PV ----
    f32x4 oacc[8] = {};
    stageK(0, 0); stageV(0, 0);
    __syncthreads();
    for (int kt = 0; kt < nkt; ++kt) {
      const int p = kt & 1;
      if (kt < nkt - 1) { stageK(p ^ 1, kt + 1); stageV(p ^ 1, kt + 1); }
      i32x4 sacc[4] = {};
      __builtin_amdgcn_s_setprio(1);
      #pragma unroll
      for (int ks = 0; ks < 2; ++ks)
        #pragma unroll
        for (int n = 0; n < 4; ++n) {
          int row = n * 16 + lr;
          i32x4 bk = *(const i32x4*)((const char*)Ks[p] + row * 128 +
                                     ((ks * 64 + lg * 16) ^ ((row & 7) << 4)));
          sacc[n] = mfma_i8(aq[ks], bk, sacc[n]);
        }
      __builtin_amdgcn_s_setprio(0);
      if (kt * 64 + 63 <= qwmin) {
        #pragma unroll
        for (int r = 0; r < 4; ++r) {
          int prow = wave * 16 + lg * 4 + r;
          #pragma unroll
          for (int n = 0; n < 4; ++n) {
            float p127 = rintf(exp2f(fmaf((float)sacc[n][r], c2, bias[r])));
            int col = n * 16 + lr;
            *(u16*)((char*)Ps + prow * 128 + ((col * 2) ^ ((prow & 7) << 4))) = f2bf(p127);
          }
        }
      } else {
        #pragma unroll
        for (int r = 0; r < 4; ++r) {
          int prow = wave * 16 + lg * 4 + r;
          int qg = qwmin + lg * 4 + r;
          #pragma unroll
          for (int n = 0; n < 4; ++n) {
            int kg = kt * 64 + n * 16 + lr;
            float a = fmaf((float)sacc[n][r], c2, bias[r]);
            float p127 = (kg <= qg) ? rintf(exp2f(a)) : 0.f;
            int col = n * 16 + lr;
            *(u16*)((char*)Ps + prow * 128 + ((col * 2) ^ ((prow & 7) << 4))) = f2bf(p127);
          }
        }
      }
      // Ps wave-private: lgkmcnt orders ds_write -> ds_read, no barrier.
      __builtin_amdgcn_s_setprio(1);
      #pragma unroll
      for (int ks = 0; ks < 2; ++ks) {
        int prow = wave * 16 + lr;
        s16x8 ap = *(const s16x8*)((const char*)Ps + prow * 128 +
                                   ((ks * 64 + lg * 16) ^ ((prow & 7) << 4)));
        #pragma unroll
        for (int n = 0; n < 8; ++n) {
          int vrow = n * 16 + lr;
          s16x8 bv = *(const s16x8*)((const char*)Vs[p] + vrow * 128 +
                                     ((ks * 64 + lg * 16) ^ ((vrow & 7) << 4)));
          oacc[n] = mfma16(ap, bv, oacc[n]);
        }
      }
      __builtin_amdgcn_s_setprio(0);
      __syncthreads();
    }
    const float pvs = sv * (1.0f / 127.0f);
    #pragma unroll
    for (int n = 0; n < 8; ++n)
      #pragma unroll
      for (int r = 0; r < 4; ++r) {
        float v = oacc[n][r] * pvs;
        gmax = fmaxf(gmax, fabsf(v));
        O[(size_t)(b * S_ + q0 + wave * 16 + lg * 4 + r) * HID + h * HD + n * 16 + lr] = v;
      }
  }
  atomic_absmax(omax, gmax, lane);
}

// ---------------------------------------------------------------------------
extern "C" void kernel_launch(void* const* d_in, const int* in_sizes, int n_in,
                              void* d_out, int out_size, void* d_ws, size_t ws_size,
                              hipStream_t stream) {
  const float* hs = (const float*)d_in[0];
  const float* Wq = (const float*)d_in[3];
  const float* Wk = (const float*)d_in[4];
  const float* Wv = (const float*)d_in[5];
  const float* Wo = (const float*)d_in[6];
  float* out = (float*)d_out;
  char* ws = (char*)d_ws;

  unsigned* sc = (unsigned*)ws;  // 0=x 1=Wq 2=Wk 3=Wv 4=Wo 5=q 6=k 7=v 8=attn_out
  size_t off = 256;
  s8* Xq = (s8*)(ws + off); off += (size_t)B_ * S_ * HID;          // 8MB
  size_t wqb_off = off;
  s8* Wqb = (s8*)(ws + off); off += (size_t)HID * HID;             // 16MB
  s8* Wkb = (s8*)(ws + off); off += (size_t)NKV * HD * HID;        // 4MB
  s8* Wvb = (s8*)(ws + off); off += (size_t)NKV * HD * HID;        // 4MB
  s8* Wob = (s8*)(ws + off); off += (size_t)HID * HID;             // 16MB
  size_t qf_off = off;
  float* qf = (float*)(ws + off); off += (size_t)B_ * S_ * HID * 4;       // 32MB
  float* kf = (float*)(ws + off); off += (size_t)B_ * S_ * NKV * HD * 4;  // 8MB
  float* vf = (float*)(ws + off); off += (size_t)B_ * S_ * NKV * HD * 4;  // 8MB
  s8* qq = (s8*)(ws + off); off += (size_t)B_ * S_ * HID;                 // 8MB
  s8* kq = (s8*)(ws + off); off += (size_t)B_ * S_ * NKV * HD;            // 2MB
  u16* vt = (u16*)(ws + off); off += (size_t)B_ * S_ * NKV * HD * 2;      // 4MB
  float2* tab = (float2*)(ws + off); off += (size_t)S_ * 64 * 8;          // 0.5MB
  float* P1 = (float*)(ws + off); off += (size_t)B_ * S_ * HID * 4;       // 32MB
  float* attnf = (float*)(ws + qf_off);  // alias qf (dead after quantqk)
  s8* attnq = (s8*)(ws + wqb_off);       // alias Wqb (dead after gemm_qkv8)
  float* P0 = (float*)(ws + qf_off);     // alias qf (attnf consumed by quant_k)

  hipFuncSetAttribute((const void*)gemm_qkv8,
                      hipFuncAttributeMaxDynamicSharedMemorySize, 131072);
  hipFuncSetAttribute((const void*)gemm_o8,
                      hipFuncAttributeMaxDynamicSharedMemorySize, 131072);

  hipMemsetAsync(sc, 0, 64, stream);

  dim3 blk(256);
  absmax5_k<<<2048, blk, 0, stream>>>(
      (const float4*)hs, (const float4*)Wq, (const float4*)Wk,
      (const float4*)Wv, (const float4*)Wo, sc);
  quant5_k<<<2048, blk, 0, stream>>>(
      (const float4*)hs, (const float4*)Wq, (const float4*)Wk,
      (const float4*)Wv, (const float4*)Wo,
      (unsigned*)Xq, (unsigned*)Wqb, (unsigned*)Wkb, (unsigned*)Wvb,
      (unsigned*)Wob, sc);
  rope_tab_k<<<256, blk, 0, stream>>>(tab);

  gemm_qkv8<<<192, 512, 131072, stream>>>(Xq, Wqb, Wkb, Wvb, qf, kf, vf, sc, sc + 7);

  rope2_k<<<dim3(512, 2), blk, 0, stream>>>(qf, kf, sc, tab);
  quantqk_k<<<dim3(512, 2), blk, 0, stream>>>((const float4*)qf, (const float4*)kf,
                                              (unsigned*)qq, (unsigned*)kq, sc);
  vquant_t_k<<<256, blk, 0, stream>>>(vf, (unsigned*)vt, sc);

  attn_k<<<256, 512, 0, stream>>>(qq, kq, vt, attnf, sc, sc + 8);

  quant_k<<<2048, blk, 0, stream>>>((const float4*)attnf, (unsigned*)attnq,
                                    B_ * S_ * HID / 4, sc, 8);
  gemm_o8<<<256, 512, 131072, stream>>>(attnq, Wob, P0, P1, sc);
  add_k<<<2048, blk, 0, stream>>>((const float4*)P0, (const float4*)P1,
                                  (float4*)out, B_ * S_ * HID / 4);
}

// Round 14
// 446.733 us; speedup vs baseline: 1.2490x; 1.0072x over previous
//
#include <hip/hip_runtime.h>
#include <math.h>

#define B_ 2
#define S_ 1024
#define HID 4096
#define NH 32
#define NKV 8
#define HD 128
#define LOG2E 1.44269504088896340736f

typedef short s16x8 __attribute__((ext_vector_type(8)));
typedef float f32x4 __attribute__((ext_vector_type(4)));
typedef int i32x4 __attribute__((ext_vector_type(4)));
typedef unsigned short u16;
typedef unsigned uint4v __attribute__((ext_vector_type(4)));
typedef signed char s8;

__device__ __forceinline__ i32x4 mfma_i8(i32x4 a, i32x4 b, i32x4 c) {
  return __builtin_amdgcn_mfma_i32_16x16x64_i8(a, b, c, 0, 0, 0);
}
__device__ __forceinline__ float get_scale(const unsigned* sc, int slot) {
  return fmaxf(__uint_as_float(sc[slot]) / 127.0f, 1e-8f);
}
__device__ __forceinline__ int q127(float x, float s) {
  return (int)fminf(fmaxf(rintf(x / s), -127.f), 127.f);
}
__device__ __forceinline__ unsigned pack4(float4 v, float s) {
  return (q127(v.x, s) & 255) | ((q127(v.y, s) & 255) << 8) |
         ((q127(v.z, s) & 255) << 16) | ((q127(v.w, s) & 255) << 24);
}
__device__ __forceinline__ float max4(float4 v) {
  return fmaxf(fmaxf(fabsf(v.x), fabsf(v.y)), fmaxf(fabsf(v.z), fabsf(v.w)));
}
__device__ __forceinline__ void gload16(const void* g, void* l) {
  __builtin_amdgcn_global_load_lds(
      (const __attribute__((address_space(1))) unsigned*)g,
      (__attribute__((address_space(3))) unsigned*)l, 16, 0, 0);
}
__device__ __forceinline__ void atomic_absmax(unsigned* out, float m, int lane) {
  #pragma unroll
  for (int o = 32; o >= 1; o >>= 1) m = fmaxf(m, __shfl_xor(m, o));
  if (lane == 0) atomicMax(out, __float_as_uint(m));
}

#define SB_() __builtin_amdgcn_sched_barrier(0)
#define PBAR() do { SB_(); __builtin_amdgcn_s_barrier(); SB_(); } while (0)
#define VM6() do { SB_(); asm volatile("s_waitcnt vmcnt(6)" ::: "memory"); } while (0)
#define VM0() do { SB_(); asm volatile("s_waitcnt vmcnt(0)" ::: "memory"); } while (0)

// work-proportional block partition for the 5 input tensors (2:4:1:1:4 /12)
__device__ __forceinline__ void tensor_pick(int blk, int& r, int& b0, int& nb) {
  if (blk < 342)       { r = 0; b0 = 0;    nb = 342; }
  else if (blk < 1024) { r = 1; b0 = 342;  nb = 682; }
  else if (blk < 1195) { r = 2; b0 = 1024; nb = 171; }
  else if (blk < 1366) { r = 3; b0 = 1195; nb = 171; }
  else                 { r = 4; b0 = 1366; nb = 682; }
}

// ---------------- fused absmax: 64B/thread contiguous batches (MLP=4) -------
__global__ void absmax5_k(const float4* __restrict__ p0, const float4* __restrict__ p1,
                          const float4* __restrict__ p2, const float4* __restrict__ p3,
                          const float4* __restrict__ p4, unsigned* __restrict__ sc) {
  int r, b0, nb;
  tensor_pick(blockIdx.x, r, b0, nb);
  const float4* x; int n4;
  if (r == 0)      { x = p0; n4 = B_ * S_ * HID / 4; }
  else if (r == 1) { x = p1; n4 = HID * HID / 4; }
  else if (r == 2) { x = p2; n4 = NKV * HD * HID / 4; }
  else if (r == 3) { x = p3; n4 = NKV * HD * HID / 4; }
  else             { x = p4; n4 = HID * HID / 4; }
  const int ng = n4 >> 2;  // groups of 4 float4 (64B)
  const int stride = nb * 256;
  float m0 = 0.f, m1 = 0.f, m2 = 0.f, m3 = 0.f;
  for (int g = (blockIdx.x - b0) * 256 + threadIdx.x; g < ng; g += stride) {
    const float4* p = x + g * 4;
    float4 v0 = p[0], v1 = p[1], v2 = p[2], v3 = p[3];
    m0 = fmaxf(m0, max4(v0)); m1 = fmaxf(m1, max4(v1));
    m2 = fmaxf(m2, max4(v2)); m3 = fmaxf(m3, max4(v3));
  }
  float m = fmaxf(fmaxf(m0, m1), fmaxf(m2, m3));
  atomic_absmax(sc + r, m, threadIdx.x & 63);
}

// ---------------- fused quantize -> s8, 64B in / 16B out per iter -----------
__global__ void quant5_k(const float4* __restrict__ p0, const float4* __restrict__ p1,
                         const float4* __restrict__ p2, const float4* __restrict__ p3,
                         const float4* __restrict__ p4,
                         unsigned* __restrict__ y0, unsigned* __restrict__ y1,
                         unsigned* __restrict__ y2, unsigned* __restrict__ y3,
                         unsigned* __restrict__ y4, const unsigned* __restrict__ sc) {
  int r, b0, nb;
  tensor_pick(blockIdx.x, r, b0, nb);
  const float4* x; unsigned* y; int n4;
  if (r == 0)      { x = p0; y = y0; n4 = B_ * S_ * HID / 4; }
  else if (r == 1) { x = p1; y = y1; n4 = HID * HID / 4; }
  else if (r == 2) { x = p2; y = y2; n4 = NKV * HD * HID / 4; }
  else if (r == 3) { x = p3; y = y3; n4 = NKV * HD * HID / 4; }
  else             { x = p4; y = y4; n4 = HID * HID / 4; }
  float s = get_scale(sc, r);
  const int ng = n4 >> 2;
  const int stride = nb * 256;
  for (int g = (blockIdx.x - b0) * 256 + threadIdx.x; g < ng; g += stride) {
    const float4* p = x + g * 4;
    float4 v0 = p[0], v1 = p[1], v2 = p[2], v3 = p[3];
    uint4v o;
    o[0] = pack4(v0, s); o[1] = pack4(v1, s);
    o[2] = pack4(v2, s); o[3] = pack4(v3, s);
    *(uint4v*)(y + g * 4) = o;
  }
}

// ---------------- generic quantize (attn output) -> s8 ----------------------
__global__ void quant_k(const float4* __restrict__ x, unsigned* __restrict__ y, int n4,
                        const unsigned* __restrict__ sc, int slot) {
  float s = get_scale(sc, slot);
  const int ng = n4 >> 2;
  int stride = gridDim.x * blockDim.x;
  for (int g = blockIdx.x * blockDim.x + threadIdx.x; g < ng; g += stride) {
    const float4* p = x + g * 4;
    float4 v0 = p[0], v1 = p[1], v2 = p[2], v3 = p[3];
    uint4v o;
    o[0] = pack4(v0, s); o[1] = pack4(v1, s);
    o[2] = pack4(v2, s); o[3] = pack4(v3, s);
    *(uint4v*)(y + g * 4) = o;
  }
}

// ---------------- split-K reduce: out = P0 + P1, 64B batches ----------------
__global__ void add_k(const float4* __restrict__ p0, const float4* __restrict__ p1,
                      float4* __restrict__ out, int n4) {
  const int ng = n4 >> 2;
  int stride = gridDim.x * blockDim.x;
  for (int g = blockIdx.x * blockDim.x + threadIdx.x; g < ng; g += stride) {
    const float4* a = p0 + g * 4;
    const float4* b = p1 + g * 4;
    float4 a0 = a[0], a1 = a[1], a2 = a[2], a3 = a[3];
    float4 b0 = b[0], b1 = b[1], b2 = b[2], b3 = b[3];
    float4* o = out + g * 4;
    o[0] = make_float4(a0.x + b0.x, a0.y + b0.y, a0.z + b0.z, a0.w + b0.w);
    o[1] = make_float4(a1.x + b1.x, a1.y + b1.y, a1.z + b1.z, a1.w + b1.w);
    o[2] = make_float4(a2.x + b2.x, a2.y + b2.y, a2.z + b2.z, a2.w + b2.w);
    o[3] = make_float4(a3.x + b3.x, a3.y + b3.y, a3.z + b3.z, a3.w + b3.w);
  }
}

// ============ 256x256 8-phase int8 GEMM (unchanged, verified) ================
__device__ __forceinline__ void rdA(const s8* slot, int wm, int lr, int lg,
                                    i32x4 af[4][2]) {
  #pragma unroll
  for (int mi = 0; mi < 4; ++mi) {
    int row = wm * 64 + mi * 16 + lr;
    const char* base = (const char*)slot + row * 128;
    int sw = (row & 7) << 4;
    #pragma unroll
    for (int ks = 0; ks < 2; ++ks)
      af[mi][ks] = *(const i32x4*)(base + ((ks * 64 + lg * 16) ^ sw));
  }
}
__device__ __forceinline__ void rdB(const s8* slot, int wn, int lr, int lg,
                                    i32x4 bf[2][2]) {
  #pragma unroll
  for (int ni = 0; ni < 2; ++ni) {
    int row = wn * 32 + ni * 16 + lr;
    const char* base = (const char*)slot + row * 128;
    int sw = (row & 7) << 4;
    #pragma unroll
    for (int ks = 0; ks < 2; ++ks)
      bf[ni][ks] = *(const i32x4*)(base + ((ks * 64 + lg * 16) ^ sw));
  }
}
template <int PM, int PN>
__device__ __forceinline__ void mfma_phase(i32x4 (&acc)[2][2][4][2],
                                           const i32x4 (&af)[4][2],
                                           const i32x4 (&bf)[2][2]) {
  __builtin_amdgcn_s_setprio(1);
  #pragma unroll
  for (int mi = 0; mi < 4; ++mi)
    #pragma unroll
    for (int ni = 0; ni < 2; ++ni)
      #pragma unroll
      for (int ks = 0; ks < 2; ++ks)
        acc[PM][PN][mi][ni] = mfma_i8(af[mi][ks], bf[ni][ks], acc[PM][PN][mi][ni]);
  __builtin_amdgcn_s_setprio(0);
}

__device__ void gemm256(const s8* __restrict__ A, const s8* __restrict__ Bm,
                        float* __restrict__ C, int Ncols, int m0, int n0,
                        int k0, int nkt, float scale, unsigned* omax, s8* S) {
  const int tid = threadIdx.x;
  const int wave = tid >> 6, lane = tid & 63;
  const int lr = lane & 15, lg = lane >> 4;
  const int wm = wave >> 2, wn = wave & 3;
  s8* SA00 = S;          s8* SA01 = S + 16384;
  s8* SB00 = S + 32768;  s8* SB01 = S + 49152;
  s8* SA10 = S + 65536;  s8* SA11 = S + 81920;
  s8* SB10 = S + 98304;  s8* SB11 = S + 114688;
  const int r0 = tid >> 3;
  const int ce = ((tid & 7) * 16) ^ ((r0 & 7) << 4);
  const s8* pa0 = A + (size_t)(m0 + r0) * HID + k0 + ce;
  const s8* pa1 = pa0 + (size_t)128 * HID;
  const s8* pb0 = Bm + (size_t)(n0 + r0) * HID + k0 + ce;
  const s8* pb1 = pb0 + (size_t)128 * HID;
  const int wdst = wave * 1024;
  i32x4 acc[2][2][4][2] = {};
  i32x4 af[4][2], bf[2][2];

  auto STG = [&](const s8* p, s8* slot, int tcol) {
    const s8* g = p + tcol * 128;
    gload16(g, slot + wdst);
    gload16(g + (size_t)64 * HID, slot + 8192 + wdst);
  };

  STG(pa0, SA00, 0); STG(pb0, SB00, 0); STG(pa1, SA01, 0); STG(pb1, SB01, 0);
  STG(pa0, SA10, 1); STG(pb1, SB11, 1); STG(pa1, SA11, 1);
  VM6(); PBAR();

  #pragma unroll 1
  for (int t = 0; t < nkt; t += 2) {
    const bool g2 = t + 2 < nkt, g3 = t + 3 < nkt;
    rdA(SA00, wm, lr, lg, af); rdB(SB00, wn, lr, lg, bf);
    STG(pb0, SB10, t + 1);
    PBAR(); mfma_phase<0, 0>(acc, af, bf); PBAR();
    rdB(SB01, wn, lr, lg, bf);
    if (g2) STG(pa0, SA00, t + 2);
    PBAR(); mfma_phase<0, 1>(acc, af, bf); PBAR();
    rdA(SA01, wm, lr, lg, af);
    if (g2) STG(pb1, SB01, t + 2);
    PBAR(); mfma_phase<1, 1>(acc, af, bf); PBAR();
    rdB(SB00, wn, lr, lg, bf);
    if (g2) STG(pa1, SA01, t + 2);
    PBAR(); mfma_phase<1, 0>(acc, af, bf);
    if (g2) { VM6(); } else { VM0(); }
    PBAR();
    rdA(SA10, wm, lr, lg, af); rdB(SB10, wn, lr, lg, bf);
    if (g2) STG(pb0, SB00, t + 2);
    PBAR(); mfma_phase<0, 0>(acc, af, bf); PBAR();
    rdB(SB11, wn, lr, lg, bf);
    if (g3) STG(pa0, SA10, t + 3);
    PBAR(); mfma_phase<0, 1>(acc, af, bf); PBAR();
    rdA(SA11, wm, lr, lg, af);
    if (g3) STG(pb1, SB11, t + 3);
    PBAR(); mfma_phase<1, 1>(acc, af, bf); PBAR();
    rdB(SB10, wn, lr, lg, bf);
    if (g3) STG(pa1, SA11, t + 3);
    PBAR(); mfma_phase<1, 0>(acc, af, bf); VM6(); PBAR();
  }

  float gm = 0.f;
  #pragma unroll
  for (int mh = 0; mh < 2; ++mh)
    #pragma unroll
    for (int nh = 0; nh < 2; ++nh)
      #pragma unroll
      for (int mi = 0; mi < 4; ++mi)
        #pragma unroll
        for (int ni = 0; ni < 2; ++ni) {
          size_t rbase = (size_t)(m0 + mh * 128 + wm * 64 + mi * 16 + lg * 4);
          int cb = n0 + nh * 128 + wn * 32 + ni * 16 + lr;
          #pragma unroll
          for (int r = 0; r < 4; ++r) {
            float v = (float)acc[mh][nh][mi][ni][r] * scale;
            gm = fmaxf(gm, fabsf(v));
            C[(rbase + r) * (size_t)Ncols + cb] = v;
          }
        }
  if (omax) atomic_absmax(omax, gm, lane);
}

__global__ __launch_bounds__(512, 1) void gemm_qkv8(
    const s8* __restrict__ Xq, const s8* __restrict__ Wqb,
    const s8* __restrict__ Wkb, const s8* __restrict__ Wvb,
    float* __restrict__ qf, float* __restrict__ kf, float* __restrict__ vf,
    const unsigned* __restrict__ sc, unsigned* __restrict__ vmax) {
  extern __shared__ __align__(16) s8 S[];
  int raw = blockIdx.x;
  int wg = (raw & 7) * 24 + (raw >> 3);
  int bx = wg & 7, by = wg >> 3;
  const s8* Bm; float* C; int Ncols, n0, sslot; unsigned* om = nullptr;
  if (by < 16)      { Bm = Wqb; C = qf; Ncols = HID;      n0 = by * 256;        sslot = 1; }
  else if (by < 20) { Bm = Wkb; C = kf; Ncols = NKV * HD; n0 = (by - 16) * 256; sslot = 2; }
  else              { Bm = Wvb; C = vf; Ncols = NKV * HD; n0 = (by - 20) * 256; sslot = 3; om = vmax; }
  float scale = get_scale(sc, 0) * get_scale(sc, sslot);
  gemm256(Xq, Bm, C, Ncols, bx * 256, n0, 0, 32, scale, om, S);
}

__global__ __launch_bounds__(512, 1) void gemm_o8(
    const s8* __restrict__ A, const s8* __restrict__ Bm,
    float* __restrict__ P0, float* __restrict__ P1,
    const unsigned* __restrict__ sc) {
  extern __shared__ __align__(16) s8 S[];
  int raw = blockIdx.x;
  int wg = (raw & 7) * 32 + (raw >> 3);
  int tile = wg >> 1, half = wg & 1;
  int by = tile & 15, bx = tile >> 4;
  float scale = get_scale(sc, 8) * get_scale(sc, 4);
  gemm256(A, Bm, half ? P1 : P0, HID, bx * 256, by * 256, half * 2048, 16,
          scale, nullptr, S);
}

// ---------------- RoPE cos/sin table (pos x 64) -----------------------------
__global__ void rope_tab_k(float2* __restrict__ tab) {
  int i = blockIdx.x * 256 + threadIdx.x;
  int pos = i >> 6, d = i & 63;
  float inv = exp2f((float)d * (-13.287712379549449f / 64.0f));
  float ang = (float)pos * inv;
  tab[i] = make_float2(cosf(ang), sinf(ang));
}

// ---------------- RoPE in-place + absmax, q & k fused, float4 ---------------
__global__ void rope2_k(float* __restrict__ qf, float* __restrict__ kf,
                        unsigned* __restrict__ sc, const float2* __restrict__ tab) {
  int reg = blockIdx.y;
  float* q = reg ? kf : qf;
  int nheads = reg ? NKV : NH;
  unsigned* om = sc + (reg ? 6 : 5);
  int total = B_ * S_ * nheads * 16;
  int stride = gridDim.x * blockDim.x;
  float m = 0.f;
  for (int i = blockIdx.x * blockDim.x + threadIdx.x; i < total; i += stride) {
    int g = i & 15;
    int h = (i >> 4) % nheads;
    int bs = i / (16 * nheads);
    int pos = bs & (S_ - 1);
    size_t base = ((size_t)bs * nheads + h) * HD + g * 4;
    float4 x1 = *(float4*)(q + base);
    float4 x2 = *(float4*)(q + base + 64);
    const float4* t = (const float4*)(tab + ((size_t)pos << 6) + g * 4);
    float4 t0 = t[0], t1 = t[1];
    float4 o1, o2;
    o1.x = x1.x * t0.x - x2.x * t0.y;  o2.x = x2.x * t0.x + x1.x * t0.y;
    o1.y = x1.y * t0.z - x2.y * t0.w;  o2.y = x2.y * t0.z + x1.y * t0.w;
    o1.z = x1.z * t1.x - x2.z * t1.y;  o2.z = x2.z * t1.x + x1.z * t1.y;
    o1.w = x1.w * t1.z - x2.w * t1.w;  o2.w = x2.w * t1.z + x1.w * t1.w;
    *(float4*)(q + base) = o1;
    *(float4*)(q + base + 64) = o2;
    m = fmaxf(m, fmaxf(max4(o1), max4(o2)));
  }
  atomic_absmax(om, m, threadIdx.x & 63);
}

// ---------------- quantize q & k fused -> s8 --------------------------------
__global__ void quantqk_k(const float4* __restrict__ qf, const float4* __restrict__ kf,
                          unsigned* __restrict__ qq, unsigned* __restrict__ kq,
                          const unsigned* __restrict__ sc) {
  int reg = blockIdx.y;
  const float4* x = reg ? kf : qf;
  unsigned* y = reg ? kq : qq;
  int n4 = reg ? (B_ * S_ * NKV * HD / 4) : (B_ * S_ * HID / 4);
  float s = get_scale(sc, reg ? 6 : 5);
  const int ng = n4 >> 2;
  int stride = gridDim.x * blockDim.x;
  for (int g = blockIdx.x * blockDim.x + threadIdx.x; g < ng; g += stride) {
    const float4* p = x + g * 4;
    float4 v0 = p[0], v1 = p[1], v2 = p[2], v3 = p[3];
    uint4v o;
    o[0] = pack4(v0, s); o[1] = pack4(v1, s);
    o[2] = pack4(v2, s); o[3] = pack4(v3, s);
    *(uint4v*)(y + g * 4) = o;
  }
}

// ---------------- V: quantize + transpose to d-pair-packed s8 layout --------
// Per (b,kvh): 64 rows j (=d>>1) x 2048B; row j, kv-tile kt occupies bytes
// kt*128 + (d&1)*64 + (kv_in ^ swz) with swz = ((j&3)<<4) baked in (so attn
// stages LINEARLY and reads with the same XOR; rule #21).
__global__ __launch_bounds__(256) void vquant_t_k(const float* __restrict__ vf,
                                                  s8* __restrict__ vt,
                                                  const unsigned* __restrict__ sc) {
  __shared__ __align__(16) s8 Ls[64][132];  // [s_local][d], padded
  float s = get_scale(sc, 7);
  int st = blockIdx.x & 15, kvh = (blockIdx.x >> 4) & 7, b = blockIdx.x >> 7;
  int s0 = st * 64;
  #pragma unroll
  for (int i = 0; i < 8; ++i) {  // 64 s x 32 float4
    int o = i * 256 + threadIdx.x;
    int sr = o >> 5, c4 = o & 31;
    float4 v = *(const float4*)(vf + ((size_t)(b * S_ + s0 + sr)) * (NKV * HD) +
                                kvh * HD + c4 * 4);
    *(unsigned*)(&Ls[sr][c4 * 4]) =
        (q127(v.x, s) & 255) | ((q127(v.y, s) & 255) << 8) |
        ((q127(v.z, s) & 255) << 16) | ((q127(v.w, s) & 255) << 24);
  }
  __syncthreads();
  s8* base = vt + (size_t)(b * NKV + kvh) * 131072 + st * 128;
  #pragma unroll
  for (int i = 0; i < 8; ++i) {  // 64 j x 2 half x 16 w  u32 writes
    int o = i * 256 + threadIdx.x;
    int j = o >> 5, half = (o >> 4) & 1, w = o & 15;
    int d = 2 * j + half;
    unsigned pk = (unsigned)(unsigned char)Ls[4 * w + 0][d] |
                  ((unsigned)(unsigned char)Ls[4 * w + 1][d] << 8) |
                  ((unsigned)(unsigned char)Ls[4 * w + 2][d] << 16) |
                  ((unsigned)(unsigned char)Ls[4 * w + 3][d] << 24);
    *(unsigned*)(base + (size_t)j * 2048 + half * 64 + ((w * 4) ^ ((j & 3) << 4))) = pk;
  }
}

// ---------------- two-pass quantized causal GQA attention (all-i8 MFMA) -----
// QK^T: i8 K=64 x2, exact int32.  PV: i8 K=64 x1 per 16-d block, exact int32
// (|sum| <= 1024*127^2 < 2^24).  P stored s8 in Ps[128][64B], row-swizzle
// col ^= ((prow>>2)&3)<<4 (writer lg == reader (lr>>2) == (prow>>2)&3).
// V in d-pair-packed s8 (see vquant_t_k).  LDS 40KB.
__global__ __launch_bounds__(512) void attn_k(
    const s8* __restrict__ Q, const s8* __restrict__ Kq, const s8* __restrict__ Vt,
    float* __restrict__ O, const unsigned* __restrict__ sc, unsigned* __restrict__ omax) {
  __shared__ __align__(16) s8 Ks[2][64 * 128];     // 2 x 8KB
  __shared__ __align__(16) s8 Vs[2][64 * 128];     // 2 x 8KB (d-pair rows)
  __shared__ __align__(16) s8 Ps[128 * 64];        // 8KB, wave-private rows
  const int tid = threadIdx.x;
  const int wave = tid >> 6, lane = tid & 63;
  const int lr = lane & 15, lg = lane >> 4;
  const int raw = blockIdx.x;
  const int xcd = raw & 7, j = raw >> 3;
  const int grp = xcd + 8 * (j >> 4);
  const int within = j & 15;
  const int b = grp >> 3, kvh = grp & 7;
  const int h = kvh * 4 + (within >> 2);
  const int qp = within & 3;
  const float sq = get_scale(sc, 5), sk = get_scale(sc, 6), sv = get_scale(sc, 7);
  const float c2 = sq * sk * 0.08838834764831845f * LOG2E;
  const float M0 = 32.0f;
  const int k_row = tid >> 3;
  const int k_cb = ((tid & 7) * 16) ^ ((k_row & 7) << 4);
  const s8* vbase = Vt + (size_t)(b * NKV + kvh) * 131072 +
                    (size_t)(tid >> 3) * 2048 + (tid & 7) * 16;
  float gmax = 0.f;

  auto stageK = [&](int buf, int kt) {
    gload16(Kq + (size_t)(b * S_ + kt * 64 + k_row) * (NKV * HD) + kvh * HD + k_cb,
            Ks[buf] + wave * 1024);
  };
  auto stageV = [&](int buf, int kt) {
    gload16(vbase + kt * 128, Vs[buf] + wave * 1024);
  };

  for (int pi = 0; pi < 2; ++pi) {
    const int qt = pi ? 7 - qp : qp;
    const int q0 = qt * 128;
    const int nkt = 2 * (qt + 1);
    const int qwmin = q0 + wave * 16;
    i32x4 aq[2];
    {
      const s8* qp_ = Q + (size_t)(b * S_ + q0 + wave * 16 + lr) * HID + h * HD + lg * 16;
      aq[0] = *(const i32x4*)(qp_);
      aq[1] = *(const i32x4*)(qp_ + 64);
    }
    float ll[4] = {0.f, 0.f, 0.f, 0.f};

    // ---- pass 1: denominator only, fixed reference M0 ----
    stageK(0, 0);
    __syncthreads();
    for (int kt = 0; kt < nkt; ++kt) {
      const int p = kt & 1;
      if (kt < nkt - 1) stageK(p ^ 1, kt + 1);
      i32x4 sacc[4] = {};
      __builtin_amdgcn_s_setprio(1);
      #pragma unroll
      for (int ks = 0; ks < 2; ++ks)
        #pragma unroll
        for (int n = 0; n < 4; ++n) {
          int row = n * 16 + lr;
          i32x4 bk = *(const i32x4*)((const char*)Ks[p] + row * 128 +
                                     ((ks * 64 + lg * 16) ^ ((row & 7) << 4)));
          sacc[n] = mfma_i8(aq[ks], bk, sacc[n]);
        }
      __builtin_amdgcn_s_setprio(0);
      if (kt * 64 + 63 <= qwmin) {
        #pragma unroll
        for (int r = 0; r < 4; ++r)
          #pragma unroll
          for (int n = 0; n < 4; ++n)
            ll[r] += exp2f(fmaf((float)sacc[n][r], c2, -M0));
      } else {
        #pragma unroll
        for (int r = 0; r < 4; ++r) {
          int qg = qwmin + lg * 4 + r;
          #pragma unroll
          for (int n = 0; n < 4; ++n) {
            int kg = kt * 64 + n * 16 + lr;
            float e = exp2f(fmaf((float)sacc[n][r], c2, -M0));
            ll[r] += (kg <= qg) ? e : 0.f;
          }
        }
      }
      __syncthreads();
    }
    float bias[4];
    #pragma unroll
    for (int r = 0; r < 4; ++r) {
      float l = ll[r];
      #pragma unroll
      for (int o = 8; o >= 1; o >>= 1) l += __shfl_xor(l, o);
      bias[r] = 6.9886846867721655f - __log2f(l) - M0;
    }

    // ---- pass 2: recompute S, quantize P (s8), PV (i8) ----
    i32x4 oacc[8] = {};
    stageK(0, 0); stageV(0, 0);
    __syncthreads();
    for (int kt = 0; kt < nkt; ++kt) {
      const int p = kt & 1;
      if (kt < nkt - 1) { stageK(p ^ 1, kt + 1); stageV(p ^ 1, kt + 1); }
      i32x4 sacc[4] = {};
      __builtin_amdgcn_s_setprio(1);
      #pragma unroll
      for (int ks = 0; ks < 2; ++ks)
        #pragma unroll
        for (int n = 0; n < 4; ++n) {
          int row = n * 16 + lr;
          i32x4 bk = *(const i32x4*)((const char*)Ks[p] + row * 128 +
                                     ((ks * 64 + lg * 16) ^ ((row & 7) << 4)));
          sacc[n] = mfma_i8(aq[ks], bk, sacc[n]);
        }
      __builtin_amdgcn_s_setprio(0);
      if (kt * 64 + 63 <= qwmin) {
        #pragma unroll
        for (int r = 0; r < 4; ++r) {
          int prow = wave * 16 + lg * 4 + r;
          s8* pr = Ps + prow * 64;
          #pragma unroll
          for (int n = 0; n < 4; ++n) {
            float p127 = rintf(exp2f(fmaf((float)sacc[n][r], c2, bias[r])));
            pr[((n * 16) ^ (lg << 4)) + lr] = (s8)(int)p127;
          }
        }
      } else {
        #pragma unroll
        for (int r = 0; r < 4; ++r) {
          int prow = wave * 16 + lg * 4 + r;
          int qg = qwmin + lg * 4 + r;
          s8* pr = Ps + prow * 64;
          #pragma unroll
          for (int n = 0; n < 4; ++n) {
            int kg = kt * 64 + n * 16 + lr;
            float a = fmaf((float)sacc[n][r], c2, bias[r]);
            float p127 = (kg <= qg) ? rintf(exp2f(a)) : 0.f;
            pr[((n * 16) ^ (lg << 4)) + lr] = (s8)(int)p127;
          }
        }
      }
      // Ps wave-private: lgkmcnt orders ds_write -> ds_read, no barrier.
      __builtin_amdgcn_s_setprio(1);
      {
        i32x4 ap = *(const i32x4*)(Ps + (wave * 16 + lr) * 64 +
                                   ((lg * 16) ^ (((lr >> 2) & 3) << 4)));
        #pragma unroll
        for (int n = 0; n < 8; ++n) {
          int jd = n * 8 + (lr >> 1);  // d>>1 for d = n*16+lr
          i32x4 bv = *(const i32x4*)((const char*)Vs[p] + jd * 128 + (lr & 1) * 64 +
                                     ((lg * 16) ^ ((jd & 3) << 4)));
          oacc[n] = mfma_i8(ap, bv, oacc[n]);
        }
      }
      __builtin_amdgcn_s_setprio(0);
      __syncthreads();
    }
    const float pvs = sv * (1.0f / 127.0f);
    #pragma unroll
    for (int n = 0; n < 8; ++n)
      #pragma unroll
      for (int r = 0; r < 4; ++r) {
        float v = (float)oacc[n][r] * pvs;
        gmax = fmaxf(gmax, fabsf(v));
        O[(size_t)(b * S_ + q0 + wave * 16 + lg * 4 + r) * HID + h * HD + n * 16 + lr] = v;
      }
  }
  atomic_absmax(omax, gmax, lane);
}

// ---------------------------------------------------------------------------
extern "C" void kernel_launch(void* const* d_in, const int* in_sizes, int n_in,
                              void* d_out, int out_size, void* d_ws, size_t ws_size,
                              hipStream_t stream) {
  const float* hs = (const float*)d_in[0];
  const float* Wq = (const float*)d_in[3];
  const float* Wk = (const float*)d_in[4];
  const float* Wv = (const float*)d_in[5];
  const float* Wo = (const float*)d_in[6];
  float* out = (float*)d_out;
  char* ws = (char*)d_ws;

  unsigned* sc = (unsigned*)ws;  // 0=x 1=Wq 2=Wk 3=Wv 4=Wo 5=q 6=k 7=v 8=attn_out
  size_t off = 256;
  s8* Xq = (s8*)(ws + off); off += (size_t)B_ * S_ * HID;
  size_t wqb_off = off;
  s8* Wqb = (s8*)(ws + off); off += (size_t)HID * HID;
  s8* Wkb = (s8*)(ws + off); off += (size_t)NKV * HD * HID;
  s8* Wvb = (s8*)(ws + off); off += (size_t)NKV * HD * HID;
  s8* Wob = (s8*)(ws + off); off += (size_t)HID * HID;
  size_t qf_off = off;
  float* qf = (float*)(ws + off); off += (size_t)B_ * S_ * HID * 4;
  float* kf = (float*)(ws + off); off += (size_t)B_ * S_ * NKV * HD * 4;
  float* vf = (float*)(ws + off); off += (size_t)B_ * S_ * NKV * HD * 4;
  s8* qq = (s8*)(ws + off); off += (size_t)B_ * S_ * HID;
  s8* kq = (s8*)(ws + off); off += (size_t)B_ * S_ * NKV * HD;
  s8* vt = (s8*)(ws + off); off += (size_t)B_ * S_ * NKV * HD;     // 2MB packed
  float2* tab = (float2*)(ws + off); off += (size_t)S_ * 64 * 8;
  float* P1 = (float*)(ws + off); off += (size_t)B_ * S_ * HID * 4;
  float* attnf = (float*)(ws + qf_off);  // alias qf (dead after quantqk)
  s8* attnq = (s8*)(ws + wqb_off);       // alias Wqb (dead after gemm_qkv8)
  float* P0 = (float*)(ws + qf_off);     // alias qf (attnf consumed by quant_k)

  hipFuncSetAttribute((const void*)gemm_qkv8,
                      hipFuncAttributeMaxDynamicSharedMemorySize, 131072);
  hipFuncSetAttribute((const void*)gemm_o8,
                      hipFuncAttributeMaxDynamicSharedMemorySize, 131072);

  hipMemsetAsync(sc, 0, 64, stream);

  dim3 blk(256);
  absmax5_k<<<2048, blk, 0, stream>>>(
      (const float4*)hs, (const float4*)Wq, (const float4*)Wk,
      (const float4*)Wv, (const float4*)Wo, sc);
  quant5_k<<<2048, blk, 0, stream>>>(
      (const float4*)hs, (const float4*)Wq, (const float4*)Wk,
      (const float4*)Wv, (const float4*)Wo,
      (unsigned*)Xq, (unsigned*)Wqb, (unsigned*)Wkb, (unsigned*)Wvb,
      (unsigned*)Wob, sc);
  rope_tab_k<<<256, blk, 0, stream>>>(tab);

  gemm_qkv8<<<192, 512, 131072, stream>>>(Xq, Wqb, Wkb, Wvb, qf, kf, vf, sc, sc + 7);

  rope2_k<<<dim3(512, 2), blk, 0, stream>>>(qf, kf, sc, tab);
  quantqk_k<<<dim3(512, 2), blk, 0, stream>>>((const float4*)qf, (const float4*)kf,
                                              (unsigned*)qq, (unsigned*)kq, sc);
  vquant_t_k<<<256, blk, 0, stream>>>(vf, vt, sc);

  attn_k<<<256, 512, 0, stream>>>(qq, kq, vt, attnf, sc, sc + 8);

  quant_k<<<2048, blk, 0, stream>>>((const float4*)attnf, (unsigned*)attnq,
                                    B_ * S_ * HID / 4, sc, 8);
  gemm_o8<<<256, 512, 131072, stream>>>(attnq, Wob, P0, P1, sc);
  add_k<<<2048, blk, 0, stream>>>((const float4*)P0, (const float4*)P1,
                                  (float4*)out, B_ * S_ * HID / 4);
}